// Round 2
// baseline (1501.232 us; speedup 1.0000x reference)
//
#include <hip/hip_runtime.h>
#include <hip/hip_bf16.h>
#include <stdint.h>
#include <stddef.h>

typedef __bf16 bf16_t;
typedef __attribute__((ext_vector_type(8))) __bf16 bf16x8;
typedef __attribute__((ext_vector_type(4))) __bf16 bf16x4;
typedef __attribute__((ext_vector_type(4))) float f32x4;

#define HDIM 1024
#define MSLOTS 16384
#define NROWS 8192  // B*S

__device__ __forceinline__ void load16_lds(const void* g, void* l) {
  __builtin_amdgcn_global_load_lds((const __attribute__((address_space(1))) void*)g,
                                   (__attribute__((address_space(3))) void*)l, 16, 0, 0);
}

// fp32 -> bf16 convert, 8 elems/thread
__global__ void cvt_f32_bf16(const float* __restrict__ X, bf16_t* __restrict__ Y, int n8) {
  int i = blockIdx.x * blockDim.x + threadIdx.x;
  if (i >= n8) return;
  float4 a = ((const float4*)X)[2 * i];
  float4 b = ((const float4*)X)[2 * i + 1];
  bf16x8 o;
  o[0] = (bf16_t)a.x; o[1] = (bf16_t)a.y; o[2] = (bf16_t)a.z; o[3] = (bf16_t)a.w;
  o[4] = (bf16_t)b.x; o[5] = (bf16_t)b.y; o[6] = (bf16_t)b.z; o[7] = (bf16_t)b.w;
  ((bf16x8*)Y)[i] = o;
}

// L2-normalize rows of length 1024 (x * rsqrt(sum(x^2)+1e-6)), fp32 in -> bf16 out
__global__ void normalize_rows(const float* __restrict__ X, bf16_t* __restrict__ Y) {
  __shared__ float part[4];
  const int t = threadIdx.x;
  const size_t row = blockIdx.x;
  float4 v = ((const float4*)(X + row * 1024))[t];
  float s = v.x * v.x + v.y * v.y + v.z * v.z + v.w * v.w;
  #pragma unroll
  for (int m = 32; m >= 1; m >>= 1) s += __shfl_xor(s, m);
  if ((t & 63) == 0) part[t >> 6] = s;
  __syncthreads();
  float tot = part[0] + part[1] + part[2] + part[3];
  float r = rsqrtf(tot + 1e-6f);
  bf16x4 o;
  o[0] = (bf16_t)(v.x * r); o[1] = (bf16_t)(v.y * r);
  o[2] = (bf16_t)(v.z * r); o[3] = (bf16_t)(v.w * r);
  *(bf16x4*)&Y[row * 1024 + t * 4] = o;
}

// V [16384,1024] f32 -> Vt [1024,16384] bf16
__global__ void transpose_cvt(const float* __restrict__ V, bf16_t* __restrict__ Vt) {
  __shared__ float tile[32][33];
  const int tx = threadIdx.x & 31, ty = threadIdx.x >> 5;  // 32 x 8
  const int h0 = blockIdx.x * 32, m0 = blockIdx.y * 32;
  #pragma unroll
  for (int j = 0; j < 32; j += 8)
    tile[ty + j][tx] = V[(size_t)(m0 + ty + j) * 1024 + h0 + tx];
  __syncthreads();
  #pragma unroll
  for (int j = 0; j < 32; j += 8)
    Vt[(size_t)(h0 + ty + j) * 16384 + m0 + tx] = (bf16_t)tile[tx][ty + j];
}

// invden[row] = 1 / sum(P[row, 0:ncols]) ; one wave per row
__global__ void row_invsum(const bf16_t* __restrict__ P, float* __restrict__ invden, int ncols) {
  const int row = blockIdx.x * 4 + (threadIdx.x >> 6);
  const int lane = threadIdx.x & 63;
  const bf16_t* p = P + (size_t)row * ncols;
  float s = 0.f;
  for (int c = lane * 8; c < ncols; c += 64 * 8) {
    bf16x8 v = *(const bf16x8*)&p[c];
    #pragma unroll
    for (int e = 0; e < 8; ++e) s += (float)v[e];
  }
  #pragma unroll
  for (int m = 32; m >= 1; m >>= 1) s += __shfl_xor(s, m);
  if (lane == 0) invden[row] = 1.0f / s;
}

// m97-style 128x128 bf16 GEMM, C = A * Bt^T. A:[rows,K], Bt:[N,K] row-major.
// EPI 0: outf = acc + bias[col]   (fp32 out)
// EPI 1: outb = usage[col]>0 ? exp(10*acc) : 0   (bf16 out)
// EPI 2: outb = acc * invden[row] (bf16 out)
template <int EPI>
__global__ void gemm_bt(const bf16_t* __restrict__ A, const bf16_t* __restrict__ Bt,
                        int K, int ldc,
                        const float* __restrict__ bias,
                        const int* __restrict__ usage,
                        const float* __restrict__ invden,
                        float* __restrict__ outf, bf16_t* __restrict__ outb) {
  __shared__ bf16_t lA[128 * 32];
  __shared__ bf16_t lB[128 * 32];
  const int t = threadIdx.x;
  const int lane = t & 63;
  const int wave = t >> 6;
  const int wm = (wave >> 1) << 6;  // wave tile origin (2x2 waves of 64x64)
  const int wn = (wave & 1) << 6;
  const int lr = lane & 15;
  const int lq = lane >> 4;

  // Tile staging: 128 rows x 32 K-cols = 8192 B per array; 256 thr x 16 B = half,
  // so each thread issues TWO global_load_lds per array (rows 0-63 and 64-127).
  const int r0 = t >> 2;         // 0..63
  const int c0 = (t & 3) * 8;    // 0,8,16,24
  const bf16_t* pA0 = A + (size_t)(blockIdx.y * 128 + r0) * K + c0;
  const bf16_t* pA1 = pA0 + (size_t)64 * K;
  const bf16_t* pB0 = Bt + (size_t)(blockIdx.x * 128 + r0) * K + c0;
  const bf16_t* pB1 = pB0 + (size_t)64 * K;

  f32x4 acc[4][4];
  #pragma unroll
  for (int i = 0; i < 4; ++i)
    #pragma unroll
    for (int j = 0; j < 4; ++j) acc[i][j] = (f32x4){0.f, 0.f, 0.f, 0.f};

  for (int k0 = 0; k0 < K; k0 += 32) {
    __syncthreads();
    load16_lds(pA0, &lA[t * 8]);
    load16_lds(pA1, &lA[2048 + t * 8]);
    load16_lds(pB0, &lB[t * 8]);
    load16_lds(pB1, &lB[2048 + t * 8]);
    pA0 += 32; pA1 += 32; pB0 += 32; pB1 += 32;
    __syncthreads();
    bf16x8 af[4], bfr[4];
    #pragma unroll
    for (int i = 0; i < 4; ++i)
      af[i] = *(const bf16x8*)&lA[(wm + i * 16 + lr) * 32 + lq * 8];
    #pragma unroll
    for (int j = 0; j < 4; ++j)
      bfr[j] = *(const bf16x8*)&lB[(wn + j * 16 + lr) * 32 + lq * 8];
    #pragma unroll
    for (int i = 0; i < 4; ++i)
      #pragma unroll
      for (int j = 0; j < 4; ++j)
        acc[i][j] = __builtin_amdgcn_mfma_f32_16x16x32_bf16(af[i], bfr[j], acc[i][j], 0, 0, 0);
  }

  // C/D layout (m89-verified): col = lane&15, row = (lane>>4)*4 + r
  const int colBase = blockIdx.x * 128 + wn + lr;
  const int rowBase = blockIdx.y * 128 + wm + lq * 4;
  #pragma unroll
  for (int j = 0; j < 4; ++j) {
    const int col = colBase + j * 16;
    float bval = 0.f;
    bool ok = true;
    if (EPI == 0) bval = bias[col];
    if (EPI == 1) ok = usage[col] > 0;
    #pragma unroll
    for (int i = 0; i < 4; ++i) {
      const int row = rowBase + i * 16;
      #pragma unroll
      for (int r = 0; r < 4; ++r) {
        const size_t idx = (size_t)(row + r) * ldc + col;
        float v = acc[i][j][r];
        if (EPI == 0) outf[idx] = v + bval;
        if (EPI == 1) outb[idx] = ok ? (bf16_t)exp2f(v * 14.426950408889634f) : (bf16_t)0.f;
        if (EPI == 2) outb[idx] = (bf16_t)(v * invden[row + r]);
      }
    }
  }
}

extern "C" void kernel_launch(void* const* d_in, const int* in_sizes, int n_in,
                              void* d_out, int out_size, void* d_ws, size_t ws_size,
                              hipStream_t stream) {
  const float* hs = (const float*)d_in[0];
  const float* Wk = (const float*)d_in[1];
  const float* bk = (const float*)d_in[2];
  // d_in[3]=Wv, d_in[4]=bv are unused by the reference
  const float* Wo = (const float*)d_in[5];
  const float* bo = (const float*)d_in[6];
  const float* mk = (const float*)d_in[7];
  const float* mv = (const float*)d_in[8];
  const int* usage = (const int*)d_in[9];
  float* out = (float*)d_out;

  char* ws = (char*)d_ws;
  size_t off = 0;
  auto alloc = [&](size_t b) -> void* {
    void* p = ws + off;
    off += (b + 255) & ~(size_t)255;
    return p;
  };
  bf16_t* hsb = (bf16_t*)alloc((size_t)NROWS * HDIM * 2);
  bf16_t* Wkb = (bf16_t*)alloc((size_t)HDIM * HDIM * 2);
  bf16_t* Wob = (bf16_t*)alloc((size_t)HDIM * HDIM * 2);
  bf16_t* mkn = (bf16_t*)alloc((size_t)MSLOTS * HDIM * 2);
  bf16_t* Vt = (bf16_t*)alloc((size_t)HDIM * MSLOTS * 2);
  bf16_t* qnb = (bf16_t*)alloc((size_t)NROWS * HDIM * 2);
  bf16_t* retrb = (bf16_t*)alloc((size_t)NROWS * HDIM * 2);
  float* invden = (float*)alloc((size_t)NROWS * 4);
  const size_t fixed = off;

  // qf (fp32 q, consumed before GEMM2) shares a region with the P chunks.
  // Pick the largest row-chunk whose P buffer fits in the remaining workspace.
  int chunk = 128;  // last-resort floor
  {
    const int cands[7] = {8192, 4096, 2048, 1024, 512, 256, 128};
    for (int ci = 0; ci < 7; ++ci) {
      size_t region = (size_t)cands[ci] * MSLOTS * 2;
      size_t qfb = (size_t)NROWS * HDIM * 4;
      if (region < qfb) region = qfb;
      if (fixed + region <= ws_size) { chunk = cands[ci]; break; }
    }
  }
  float* qf = (float*)(ws + fixed);
  bf16_t* P = (bf16_t*)(ws + fixed);

  // ---- stage 0: dtype prep ----
  cvt_f32_bf16<<<(NROWS * HDIM / 8 + 255) / 256, 256, 0, stream>>>(hs, hsb, NROWS * HDIM / 8);
  cvt_f32_bf16<<<(HDIM * HDIM / 8 + 255) / 256, 256, 0, stream>>>(Wk, Wkb, HDIM * HDIM / 8);
  cvt_f32_bf16<<<(HDIM * HDIM / 8 + 255) / 256, 256, 0, stream>>>(Wo, Wob, HDIM * HDIM / 8);
  normalize_rows<<<MSLOTS, 256, 0, stream>>>(mk, mkn);
  transpose_cvt<<<dim3(HDIM / 32, MSLOTS / 32), 256, 0, stream>>>(mv, Vt);

  // ---- stage 1: q = hs @ Wk^T + bk (fp32), then normalize -> qn bf16 ----
  gemm_bt<0><<<dim3(HDIM / 128, NROWS / 128), 256, 0, stream>>>(
      hsb, Wkb, HDIM, HDIM, bk, nullptr, nullptr, qf, nullptr);
  normalize_rows<<<NROWS, 256, 0, stream>>>(qf, qnb);

  // ---- stage 2/3: P = exp(10 * qn@mkn^T) masked; retrieved = (P @ V) / rowsum(P) ----
  for (int c = 0; c < NROWS; c += chunk) {
    gemm_bt<1><<<dim3(MSLOTS / 128, chunk / 128), 256, 0, stream>>>(
        qnb + (size_t)c * HDIM, mkn, HDIM, MSLOTS, nullptr, usage, nullptr, nullptr, P);
    row_invsum<<<chunk / 4, 256, 0, stream>>>(P, invden, MSLOTS);
    gemm_bt<2><<<dim3(HDIM / 128, chunk / 128), 256, 0, stream>>>(
        P, Vt, MSLOTS, HDIM, nullptr, nullptr, invden, nullptr, retrb + (size_t)c * HDIM);
  }

  // ---- stage 4: out = retrieved @ Wo^T + bo (fp32) ----
  gemm_bt<0><<<dim3(HDIM / 128, NROWS / 128), 256, 0, stream>>>(
      retrb, Wob, HDIM, HDIM, bo, nullptr, nullptr, out, nullptr);
}

// Round 3
// 1279.870 us; speedup vs baseline: 1.1730x; 1.1730x over previous
//
#include <hip/hip_runtime.h>
#include <hip/hip_bf16.h>
#include <stdint.h>
#include <stddef.h>

typedef __bf16 bf16_t;
typedef __attribute__((ext_vector_type(8))) __bf16 bf16x8;
typedef __attribute__((ext_vector_type(4))) __bf16 bf16x4;
typedef __attribute__((ext_vector_type(4))) float f32x4;

#define HDIM 1024
#define MSLOTS 16384
#define NROWS 8192  // B*S
#define KSPLIT 4    // split-K factor for the PV GEMM

__device__ __forceinline__ void load16_lds(const void* g, void* l) {
  __builtin_amdgcn_global_load_lds((const __attribute__((address_space(1))) void*)g,
                                   (__attribute__((address_space(3))) void*)l, 16, 0, 0);
}

// fp32 -> bf16 convert, 8 elems/thread
__global__ void cvt_f32_bf16(const float* __restrict__ X, bf16_t* __restrict__ Y, int n8) {
  int i = blockIdx.x * blockDim.x + threadIdx.x;
  if (i >= n8) return;
  float4 a = ((const float4*)X)[2 * i];
  float4 b = ((const float4*)X)[2 * i + 1];
  bf16x8 o;
  o[0] = (bf16_t)a.x; o[1] = (bf16_t)a.y; o[2] = (bf16_t)a.z; o[3] = (bf16_t)a.w;
  o[4] = (bf16_t)b.x; o[5] = (bf16_t)b.y; o[6] = (bf16_t)b.z; o[7] = (bf16_t)b.w;
  ((bf16x8*)Y)[i] = o;
}

// L2-normalize rows of length 1024 (x * rsqrt(sum(x^2)+1e-6)), fp32 in -> bf16 out
__global__ void normalize_rows(const float* __restrict__ X, bf16_t* __restrict__ Y) {
  __shared__ float part[4];
  const int t = threadIdx.x;
  const size_t row = blockIdx.x;
  float4 v = ((const float4*)(X + row * 1024))[t];
  float s = v.x * v.x + v.y * v.y + v.z * v.z + v.w * v.w;
  #pragma unroll
  for (int m = 32; m >= 1; m >>= 1) s += __shfl_xor(s, m);
  if ((t & 63) == 0) part[t >> 6] = s;
  __syncthreads();
  float tot = part[0] + part[1] + part[2] + part[3];
  float r = rsqrtf(tot + 1e-6f);
  bf16x4 o;
  o[0] = (bf16_t)(v.x * r); o[1] = (bf16_t)(v.y * r);
  o[2] = (bf16_t)(v.z * r); o[3] = (bf16_t)(v.w * r);
  *(bf16x4*)&Y[row * 1024 + t * 4] = o;
}

// V [16384,1024] f32 -> Vt [1024,16384] bf16
__global__ void transpose_cvt(const float* __restrict__ V, bf16_t* __restrict__ Vt) {
  __shared__ float tile[32][33];
  const int tx = threadIdx.x & 31, ty = threadIdx.x >> 5;  // 32 x 8
  const int h0 = blockIdx.x * 32, m0 = blockIdx.y * 32;
  #pragma unroll
  for (int j = 0; j < 32; j += 8)
    tile[ty + j][tx] = V[(size_t)(m0 + ty + j) * 1024 + h0 + tx];
  __syncthreads();
  #pragma unroll
  for (int j = 0; j < 32; j += 8)
    Vt[(size_t)(h0 + ty + j) * 16384 + m0 + tx] = (bf16_t)tile[tx][ty + j];
}

__global__ void zero_f32(float* __restrict__ p, int n) {
  int i = blockIdx.x * blockDim.x + threadIdx.x;
  if (i < n) p[i] = 0.f;
}

// sum KSPLIT fp32 partial slabs, scale by 1/den[row], store bf16. 4 elems/thread.
__global__ void reduce_scale(const float* __restrict__ part, size_t partStride,
                             const float* __restrict__ den, bf16_t* __restrict__ out, int n4) {
  int i = blockIdx.x * blockDim.x + threadIdx.x;
  if (i >= n4) return;
  float4 s = ((const float4*)part)[i];
  #pragma unroll
  for (int k = 1; k < KSPLIT; ++k) {
    float4 t = ((const float4*)(part + (size_t)k * partStride))[i];
    s.x += t.x; s.y += t.y; s.z += t.z; s.w += t.w;
  }
  const int row = (i * 4) >> 10;  // HDIM=1024
  const float r = 1.0f / den[row];
  bf16x4 o;
  o[0] = (bf16_t)(s.x * r); o[1] = (bf16_t)(s.y * r);
  o[2] = (bf16_t)(s.z * r); o[3] = (bf16_t)(s.w * r);
  ((bf16x4*)out)[i] = o;
}

// m97-style 128x128 bf16 GEMM, C = A * Bt^T. A:[rows,ldk], Bt:[N,ldk] row-major.
// EPI 0: outf = acc + bias[col]                           (fp32 out)
// EPI 1: outb = usage[col]>0 ? exp(10*acc) : 0 (bf16 out) + atomic row-sums into den
// EPI 3: split-K partial: outf[z-slab] = acc              (fp32 out, kLen per z-block)
template <int EPI>
__global__ void gemm_bt(const bf16_t* __restrict__ A, const bf16_t* __restrict__ Bt,
                        int ldk, int kLen, int ldc,
                        const float* __restrict__ bias,
                        const int* __restrict__ usage,
                        float* __restrict__ den,
                        float* __restrict__ outf, bf16_t* __restrict__ outb,
                        size_t partStride) {
  __shared__ bf16_t lA[128 * 32];
  __shared__ bf16_t lB[128 * 32];
  const int t = threadIdx.x;
  const int lane = t & 63;
  const int wave = t >> 6;
  const int wm = (wave >> 1) << 6;  // wave tile origin (2x2 waves of 64x64)
  const int wn = (wave & 1) << 6;
  const int lr = lane & 15;
  const int lq = lane >> 4;

  const int kstart = (EPI == 3) ? blockIdx.z * kLen : 0;

  // Tile staging: 128 rows x 32 K-cols = 8192 B per array; 256 thr x 16 B = half,
  // so each thread issues TWO global_load_lds per array (rows 0-63 and 64-127).
  const int r0 = t >> 2;         // 0..63
  const int c0 = (t & 3) * 8;    // 0,8,16,24
  const bf16_t* pA0 = A + (size_t)(blockIdx.y * 128 + r0) * ldk + kstart + c0;
  const bf16_t* pA1 = pA0 + (size_t)64 * ldk;
  const bf16_t* pB0 = Bt + (size_t)(blockIdx.x * 128 + r0) * ldk + kstart + c0;
  const bf16_t* pB1 = pB0 + (size_t)64 * ldk;

  f32x4 acc[4][4];
  #pragma unroll
  for (int i = 0; i < 4; ++i)
    #pragma unroll
    for (int j = 0; j < 4; ++j) acc[i][j] = (f32x4){0.f, 0.f, 0.f, 0.f};

  for (int k0 = 0; k0 < kLen; k0 += 32) {
    __syncthreads();
    load16_lds(pA0, &lA[t * 8]);
    load16_lds(pA1, &lA[2048 + t * 8]);
    load16_lds(pB0, &lB[t * 8]);
    load16_lds(pB1, &lB[2048 + t * 8]);
    pA0 += 32; pA1 += 32; pB0 += 32; pB1 += 32;
    __syncthreads();
    bf16x8 af[4], bfr[4];
    #pragma unroll
    for (int i = 0; i < 4; ++i)
      af[i] = *(const bf16x8*)&lA[(wm + i * 16 + lr) * 32 + lq * 8];
    #pragma unroll
    for (int j = 0; j < 4; ++j)
      bfr[j] = *(const bf16x8*)&lB[(wn + j * 16 + lr) * 32 + lq * 8];
    #pragma unroll
    for (int i = 0; i < 4; ++i)
      #pragma unroll
      for (int j = 0; j < 4; ++j)
        acc[i][j] = __builtin_amdgcn_mfma_f32_16x16x32_bf16(af[i], bfr[j], acc[i][j], 0, 0, 0);
  }

  // C/D layout (m89-verified): col = lane&15, row = (lane>>4)*4 + r
  const int colBase = blockIdx.x * 128 + wn + lr;
  const int rowBase = blockIdx.y * 128 + wm + lq * 4;

  if (EPI == 3) outf += (size_t)blockIdx.z * partStride;

  float rs[4][4];  // per-(i,r) row-sum accumulators (EPI==1)
  if (EPI == 1) {
    #pragma unroll
    for (int i = 0; i < 4; ++i)
      #pragma unroll
      for (int r = 0; r < 4; ++r) rs[i][r] = 0.f;
  }

  #pragma unroll
  for (int j = 0; j < 4; ++j) {
    const int col = colBase + j * 16;
    float bval = 0.f;
    bool ok = true;
    if (EPI == 0) bval = bias[col];
    if (EPI == 1) ok = usage[col] > 0;
    #pragma unroll
    for (int i = 0; i < 4; ++i) {
      const int row = rowBase + i * 16;
      #pragma unroll
      for (int r = 0; r < 4; ++r) {
        const size_t idx = (size_t)(row + r) * ldc + col;
        float v = acc[i][j][r];
        if (EPI == 0) outf[idx] = v + bval;
        if (EPI == 1) {
          float e = ok ? exp2f(v * 14.426950408889634f) : 0.f;
          rs[i][r] += e;
          outb[idx] = (bf16_t)e;
        }
        if (EPI == 3) outf[idx] = v;
      }
    }
  }

  if (EPI == 1) {
    // reduce rs over the 16-lane col group (lr), then one atomic per row per wave
    #pragma unroll
    for (int i = 0; i < 4; ++i)
      #pragma unroll
      for (int r = 0; r < 4; ++r) {
        float s = rs[i][r];
        s += __shfl_xor(s, 1);
        s += __shfl_xor(s, 2);
        s += __shfl_xor(s, 4);
        s += __shfl_xor(s, 8);
        if (lr == 0) atomicAdd(&den[rowBase + i * 16 + r], s);
      }
  }
}

extern "C" void kernel_launch(void* const* d_in, const int* in_sizes, int n_in,
                              void* d_out, int out_size, void* d_ws, size_t ws_size,
                              hipStream_t stream) {
  const float* hs = (const float*)d_in[0];
  const float* Wk = (const float*)d_in[1];
  const float* bk = (const float*)d_in[2];
  // d_in[3]=Wv, d_in[4]=bv are unused by the reference
  const float* Wo = (const float*)d_in[5];
  const float* bo = (const float*)d_in[6];
  const float* mk = (const float*)d_in[7];
  const float* mv = (const float*)d_in[8];
  const int* usage = (const int*)d_in[9];
  float* out = (float*)d_out;

  char* ws = (char*)d_ws;
  size_t off = 0;
  auto alloc = [&](size_t b) -> void* {
    void* p = ws + off;
    off += (b + 255) & ~(size_t)255;
    return p;
  };
  bf16_t* hsb = (bf16_t*)alloc((size_t)NROWS * HDIM * 2);
  bf16_t* Wkb = (bf16_t*)alloc((size_t)HDIM * HDIM * 2);
  bf16_t* Wob = (bf16_t*)alloc((size_t)HDIM * HDIM * 2);
  bf16_t* mkn = (bf16_t*)alloc((size_t)MSLOTS * HDIM * 2);
  bf16_t* Vt = (bf16_t*)alloc((size_t)HDIM * MSLOTS * 2);
  bf16_t* qnb = (bf16_t*)alloc((size_t)NROWS * HDIM * 2);
  bf16_t* retrb = (bf16_t*)alloc((size_t)NROWS * HDIM * 2);
  float* den = (float*)alloc((size_t)NROWS * 4);
  const size_t fixed = off;

  // Overlay region: qf (fp32 q, consumed before GEMM2) shares space with
  // [P chunk][split-K partials]. Pick the largest row-chunk that fits.
  int chunk = 128;  // last-resort floor
  {
    const int cands[7] = {8192, 4096, 2048, 1024, 512, 256, 128};
    for (int ci = 0; ci < 7; ++ci) {
      size_t region = (size_t)cands[ci] * (MSLOTS * 2 + HDIM * 4 * KSPLIT);
      size_t qfb = (size_t)NROWS * HDIM * 4;
      if (region < qfb) region = qfb;
      if (fixed + region <= ws_size) { chunk = cands[ci]; break; }
    }
  }
  float* qf = (float*)(ws + fixed);
  bf16_t* P = (bf16_t*)(ws + fixed);
  float* part = (float*)(ws + fixed + (size_t)chunk * MSLOTS * 2);
  const size_t partStride = (size_t)chunk * HDIM;

  // ---- stage 0: dtype prep ----
  cvt_f32_bf16<<<(NROWS * HDIM / 8 + 255) / 256, 256, 0, stream>>>(hs, hsb, NROWS * HDIM / 8);
  cvt_f32_bf16<<<(HDIM * HDIM / 8 + 255) / 256, 256, 0, stream>>>(Wk, Wkb, HDIM * HDIM / 8);
  cvt_f32_bf16<<<(HDIM * HDIM / 8 + 255) / 256, 256, 0, stream>>>(Wo, Wob, HDIM * HDIM / 8);
  normalize_rows<<<MSLOTS, 256, 0, stream>>>(mk, mkn);
  transpose_cvt<<<dim3(HDIM / 32, MSLOTS / 32), 256, 0, stream>>>(mv, Vt);

  // ---- stage 1: q = hs @ Wk^T + bk (fp32), then normalize -> qn bf16 ----
  gemm_bt<0><<<dim3(HDIM / 128, NROWS / 128), 256, 0, stream>>>(
      hsb, Wkb, HDIM, HDIM, HDIM, bk, nullptr, nullptr, qf, nullptr, 0);
  normalize_rows<<<NROWS, 256, 0, stream>>>(qf, qnb);

  // ---- stage 2/3: P = exp(10 * qn@mkn^T) masked (+row sums); retrieved = P@V / den ----
  for (int c = 0; c < NROWS; c += chunk) {
    zero_f32<<<(chunk + 255) / 256, 256, 0, stream>>>(den, chunk);
    gemm_bt<1><<<dim3(MSLOTS / 128, chunk / 128), 256, 0, stream>>>(
        qnb + (size_t)c * HDIM, mkn, HDIM, HDIM, MSLOTS, nullptr, usage, den, nullptr, P, 0);
    gemm_bt<3><<<dim3(HDIM / 128, chunk / 128, KSPLIT), 256, 0, stream>>>(
        P, Vt, MSLOTS, MSLOTS / KSPLIT, HDIM, nullptr, nullptr, nullptr, part, nullptr,
        partStride);
    reduce_scale<<<(chunk * HDIM / 4 + 255) / 256, 256, 0, stream>>>(
        part, partStride, den, retrb + (size_t)c * HDIM, chunk * HDIM / 4);
  }

  // ---- stage 4: out = retrieved @ Wo^T + bo (fp32) ----
  gemm_bt<0><<<dim3(HDIM / 128, NROWS / 128), 256, 0, stream>>>(
      retrb, Wob, HDIM, HDIM, HDIM, bo, nullptr, nullptr, out, nullptr, 0);
}

// Round 4
// 1179.505 us; speedup vs baseline: 1.2728x; 1.0851x over previous
//
#include <hip/hip_runtime.h>
#include <hip/hip_bf16.h>
#include <stdint.h>
#include <stddef.h>

typedef __bf16 bf16_t;
typedef __attribute__((ext_vector_type(8))) __bf16 bf16x8;
typedef __attribute__((ext_vector_type(4))) __bf16 bf16x4;
typedef __attribute__((ext_vector_type(4))) float f32x4;

#define HDIM 1024
#define MSLOTS 16384
#define NROWS 8192  // B*S

__device__ __forceinline__ void load16_lds(const void* g, void* l) {
  __builtin_amdgcn_global_load_lds((const __attribute__((address_space(1))) void*)g,
                                   (__attribute__((address_space(3))) void*)l, 16, 0, 0);
}

// smalls[0] = count of used slots, smalls[1] = count padded up to multiple of 512
__global__ void init_compact(int* __restrict__ smalls, int* __restrict__ cmask) {
  int i = blockIdx.x * blockDim.x + threadIdx.x;
  if (i < MSLOTS) cmask[i] = 0;
  if (i == 0) smalls[0] = 0;
}

__global__ void finalize_count(int* __restrict__ smalls) {
  smalls[1] = ((smalls[0] + 511) >> 9) << 9;
}

// fp32 -> bf16 convert, 8 elems/thread
__global__ void cvt_f32_bf16(const float* __restrict__ X, bf16_t* __restrict__ Y, int n8) {
  int i = blockIdx.x * blockDim.x + threadIdx.x;
  if (i >= n8) return;
  float4 a = ((const float4*)X)[2 * i];
  float4 b = ((const float4*)X)[2 * i + 1];
  bf16x8 o;
  o[0] = (bf16_t)a.x; o[1] = (bf16_t)a.y; o[2] = (bf16_t)a.z; o[3] = (bf16_t)a.w;
  o[4] = (bf16_t)b.x; o[5] = (bf16_t)b.y; o[6] = (bf16_t)b.z; o[7] = (bf16_t)b.w;
  ((bf16x8*)Y)[i] = o;
}

// L2-normalize rows of length 1024, fp32 in -> bf16 out (for q)
__global__ void normalize_rows(const float* __restrict__ X, bf16_t* __restrict__ Y) {
  __shared__ float part[4];
  const int t = threadIdx.x;
  const size_t row = blockIdx.x;
  float4 v = ((const float4*)(X + row * 1024))[t];
  float s = v.x * v.x + v.y * v.y + v.z * v.z + v.w * v.w;
  #pragma unroll
  for (int m = 32; m >= 1; m >>= 1) s += __shfl_xor(s, m);
  if ((t & 63) == 0) part[t >> 6] = s;
  __syncthreads();
  float tot = part[0] + part[1] + part[2] + part[3];
  float r = rsqrtf(tot + 1e-6f);
  bf16x4 o;
  o[0] = (bf16_t)(v.x * r); o[1] = (bf16_t)(v.y * r);
  o[2] = (bf16_t)(v.z * r); o[3] = (bf16_t)(v.w * r);
  *(bf16x4*)&Y[row * 1024 + t * 4] = o;
}

// normalize mk rows; compact used slots (usage>0) into cmkn via atomic counter.
// Order is irrelevant: softmax denominator and PV are order-independent sums.
__global__ void normalize_gather_mk(const float* __restrict__ mk, const int* __restrict__ usage,
                                    bf16_t* __restrict__ cmkn, int* __restrict__ posmap,
                                    int* __restrict__ cmask, int* __restrict__ smalls) {
  __shared__ float part[4];
  __shared__ int spos;
  const int t = threadIdx.x;
  const int slot = blockIdx.x;
  if (usage[slot] <= 0) return;  // block-uniform
  float4 v = ((const float4*)(mk + (size_t)slot * 1024))[t];
  float s = v.x * v.x + v.y * v.y + v.z * v.z + v.w * v.w;
  #pragma unroll
  for (int m = 32; m >= 1; m >>= 1) s += __shfl_xor(s, m);
  if ((t & 63) == 0) part[t >> 6] = s;
  __syncthreads();
  float tot = part[0] + part[1] + part[2] + part[3];
  float r = rsqrtf(tot + 1e-6f);
  if (t == 0) spos = atomicAdd(&smalls[0], 1);
  __syncthreads();
  const int pos = spos;
  bf16x4 o;
  o[0] = (bf16_t)(v.x * r); o[1] = (bf16_t)(v.y * r);
  o[2] = (bf16_t)(v.z * r); o[3] = (bf16_t)(v.w * r);
  *(bf16x4*)&cmkn[(size_t)pos * 1024 + t * 4] = o;
  if (t == 0) { posmap[pos] = slot; cmask[pos] = 1; }
}

// zero cmkn rows [cnt, mpad)
__global__ void pad_zero_cmkn(const int* __restrict__ smalls, bf16_t* __restrict__ cmkn) {
  const int row = smalls[0] + blockIdx.x;
  if (row >= smalls[1]) return;
  bf16x4 z;
  z[0] = z[1] = z[2] = z[3] = (bf16_t)0.f;
  *(bf16x4*)&cmkn[(size_t)row * 1024 + threadIdx.x * 4] = z;
}

// cVt[h][pos] = pos<cnt ? mv[posmap[pos]][h] : 0, for pos < mpad
__global__ void transpose_gather(const float* __restrict__ mv, const int* __restrict__ posmap,
                                 const int* __restrict__ smalls, bf16_t* __restrict__ cVt) {
  __shared__ float tile[32][33];
  const int cnt = smalls[0], mpad = smalls[1];
  const int p0 = blockIdx.y * 32;
  if (p0 >= mpad) return;
  const int tx = threadIdx.x & 31, ty = threadIdx.x >> 5;  // 32 x 8
  const int h0 = blockIdx.x * 32;
  #pragma unroll
  for (int j = 0; j < 32; j += 8) {
    const int pos = p0 + ty + j;
    float val = 0.f;
    if (pos < cnt) val = mv[(size_t)posmap[pos] * 1024 + h0 + tx];
    tile[ty + j][tx] = val;
  }
  __syncthreads();
  #pragma unroll
  for (int j = 0; j < 32; j += 8)
    cVt[(size_t)(h0 + ty + j) * MSLOTS + p0 + tx] = (bf16_t)tile[tx][ty + j];
}

__global__ void zero_f32(float* __restrict__ p, int n) {
  int i = blockIdx.x * blockDim.x + threadIdx.x;
  if (i < n) p[i] = 0.f;
}

// sum ks fp32 partial slabs, scale by 1/den[row], store bf16. 4 elems/thread.
__global__ void reduce_scale(const float* __restrict__ part, size_t partStride, int ks,
                             const float* __restrict__ den, bf16_t* __restrict__ out, int n4) {
  int i = blockIdx.x * blockDim.x + threadIdx.x;
  if (i >= n4) return;
  float4 s = ((const float4*)part)[i];
  for (int k = 1; k < ks; ++k) {
    float4 t = ((const float4*)(part + (size_t)k * partStride))[i];
    s.x += t.x; s.y += t.y; s.z += t.z; s.w += t.w;
  }
  const int row = (i * 4) >> 10;  // HDIM=1024
  const float r = 1.0f / den[row];
  bf16x4 o;
  o[0] = (bf16_t)(s.x * r); o[1] = (bf16_t)(s.y * r);
  o[2] = (bf16_t)(s.z * r); o[3] = (bf16_t)(s.w * r);
  ((bf16x4*)out)[i] = o;
}

// m97-style 128x128 bf16 GEMM, C = A * Bt^T. A:[rows,ldk], Bt:[N,ldk] row-major.
// EPI 0: outf = acc + bias[col]                           (fp32 out)
// EPI 1: outb = cmask[col] ? exp(10*acc) : 0 (bf16) + atomic row-sums into den;
//        x-blocks beyond mpad exit
// EPI 3: split-K partial over K=mpad (device): outf[z-slab] = acc (fp32)
template <int EPI>
__global__ void gemm_bt(const bf16_t* __restrict__ A, const bf16_t* __restrict__ Bt,
                        int ldk, int kLenIn, int ldc,
                        const float* __restrict__ bias,
                        const int* __restrict__ usage,
                        float* __restrict__ den,
                        float* __restrict__ outf, bf16_t* __restrict__ outb,
                        size_t partStride, const int* __restrict__ smalls, int ks) {
  __shared__ bf16_t lA[128 * 32];
  __shared__ bf16_t lB[128 * 32];
  const int t = threadIdx.x;
  const int lane = t & 63;
  const int wave = t >> 6;
  const int wm = (wave >> 1) << 6;  // wave tile origin (2x2 waves of 64x64)
  const int wn = (wave & 1) << 6;
  const int lr = lane & 15;
  const int lq = lane >> 4;

  int kLen = kLenIn;
  int kstart = 0;
  if (EPI == 1) {
    if (blockIdx.x * 128 >= smalls[1]) return;  // compacted N bound (block-uniform)
  }
  if (EPI == 3) {
    kLen = smalls[1] / ks;  // mpad % 512 == 0 -> kLen % 32 == 0
    kstart = blockIdx.z * kLen;
  }

  // Tile staging: 128 rows x 32 K-cols = 8192 B per array; 256 thr x 16 B = half,
  // so each thread issues TWO global_load_lds per array (rows 0-63 and 64-127).
  const int r0 = t >> 2;         // 0..63
  const int c0 = (t & 3) * 8;    // 0,8,16,24
  const bf16_t* pA0 = A + (size_t)(blockIdx.y * 128 + r0) * ldk + kstart + c0;
  const bf16_t* pA1 = pA0 + (size_t)64 * ldk;
  const bf16_t* pB0 = Bt + (size_t)(blockIdx.x * 128 + r0) * ldk + kstart + c0;
  const bf16_t* pB1 = pB0 + (size_t)64 * ldk;

  f32x4 acc[4][4];
  #pragma unroll
  for (int i = 0; i < 4; ++i)
    #pragma unroll
    for (int j = 0; j < 4; ++j) acc[i][j] = (f32x4){0.f, 0.f, 0.f, 0.f};

  for (int k0 = 0; k0 < kLen; k0 += 32) {
    __syncthreads();
    load16_lds(pA0, &lA[t * 8]);
    load16_lds(pA1, &lA[2048 + t * 8]);
    load16_lds(pB0, &lB[t * 8]);
    load16_lds(pB1, &lB[2048 + t * 8]);
    pA0 += 32; pA1 += 32; pB0 += 32; pB1 += 32;
    __syncthreads();
    bf16x8 af[4], bfr[4];
    #pragma unroll
    for (int i = 0; i < 4; ++i)
      af[i] = *(const bf16x8*)&lA[(wm + i * 16 + lr) * 32 + lq * 8];
    #pragma unroll
    for (int j = 0; j < 4; ++j)
      bfr[j] = *(const bf16x8*)&lB[(wn + j * 16 + lr) * 32 + lq * 8];
    #pragma unroll
    for (int i = 0; i < 4; ++i)
      #pragma unroll
      for (int j = 0; j < 4; ++j)
        acc[i][j] = __builtin_amdgcn_mfma_f32_16x16x32_bf16(af[i], bfr[j], acc[i][j], 0, 0, 0);
  }

  // C/D layout (m89-verified): col = lane&15, row = (lane>>4)*4 + r
  const int colBase = blockIdx.x * 128 + wn + lr;
  const int rowBase = blockIdx.y * 128 + wm + lq * 4;

  if (EPI == 3) outf += (size_t)blockIdx.z * partStride;

  float rs[4][4];  // per-(i,r) row-sum accumulators (EPI==1)
  if (EPI == 1) {
    #pragma unroll
    for (int i = 0; i < 4; ++i)
      #pragma unroll
      for (int r = 0; r < 4; ++r) rs[i][r] = 0.f;
  }

  #pragma unroll
  for (int j = 0; j < 4; ++j) {
    const int col = colBase + j * 16;
    float bval = 0.f;
    bool ok = true;
    if (EPI == 0) bval = bias[col];
    if (EPI == 1) ok = usage[col] > 0;  // usage = compacted mask
    #pragma unroll
    for (int i = 0; i < 4; ++i) {
      const int row = rowBase + i * 16;
      #pragma unroll
      for (int r = 0; r < 4; ++r) {
        const size_t idx = (size_t)(row + r) * ldc + col;
        float v = acc[i][j][r];
        if (EPI == 0) outf[idx] = v + bval;
        if (EPI == 1) {
          float e = ok ? exp2f(v * 14.426950408889634f) : 0.f;
          rs[i][r] += e;
          outb[idx] = (bf16_t)e;
        }
        if (EPI == 3) outf[idx] = v;
      }
    }
  }

  if (EPI == 1) {
    // reduce rs over the 16-lane col group (lr), then one atomic per row per wave
    #pragma unroll
    for (int i = 0; i < 4; ++i)
      #pragma unroll
      for (int r = 0; r < 4; ++r) {
        float s = rs[i][r];
        s += __shfl_xor(s, 1);
        s += __shfl_xor(s, 2);
        s += __shfl_xor(s, 4);
        s += __shfl_xor(s, 8);
        if (lr == 0) atomicAdd(&den[rowBase + i * 16 + r], s);
      }
  }
}

extern "C" void kernel_launch(void* const* d_in, const int* in_sizes, int n_in,
                              void* d_out, int out_size, void* d_ws, size_t ws_size,
                              hipStream_t stream) {
  const float* hs = (const float*)d_in[0];
  const float* Wk = (const float*)d_in[1];
  const float* bk = (const float*)d_in[2];
  // d_in[3]=Wv, d_in[4]=bv are unused by the reference
  const float* Wo = (const float*)d_in[5];
  const float* bo = (const float*)d_in[6];
  const float* mk = (const float*)d_in[7];
  const float* mv = (const float*)d_in[8];
  const int* usage = (const int*)d_in[9];
  float* out = (float*)d_out;

  char* ws = (char*)d_ws;
  size_t off = 0;
  auto alloc = [&](size_t b) -> void* {
    void* p = ws + off;
    off += (b + 255) & ~(size_t)255;
    return p;
  };
  bf16_t* hsb = (bf16_t*)alloc((size_t)NROWS * HDIM * 2);
  bf16_t* Wkb = (bf16_t*)alloc((size_t)HDIM * HDIM * 2);
  bf16_t* Wob = (bf16_t*)alloc((size_t)HDIM * HDIM * 2);
  bf16_t* cmkn = (bf16_t*)alloc((size_t)MSLOTS * HDIM * 2);
  bf16_t* cVt = (bf16_t*)alloc((size_t)HDIM * MSLOTS * 2);
  bf16_t* qnb = (bf16_t*)alloc((size_t)NROWS * HDIM * 2);
  bf16_t* retrb = (bf16_t*)alloc((size_t)NROWS * HDIM * 2);
  float* den = (float*)alloc((size_t)NROWS * 4);
  int* posmap = (int*)alloc((size_t)MSLOTS * 4);
  int* cmask = (int*)alloc((size_t)MSLOTS * 4);
  int* smalls = (int*)alloc(256 * 4);
  const size_t fixed = off;

  // Overlay region: qf (fp32 q) shares space with [P chunk][split-K partials].
  // Ladder of (chunk, ks) by descending G3 parallelism; pick first that fits.
  int chunk = 128, ksplit = 4;
  {
    const int cc[7] = {2048, 2048, 1024, 1024, 512, 256, 128};
    const int kk[7] = {16, 8, 16, 8, 8, 8, 4};
    for (int ci = 0; ci < 7; ++ci) {
      size_t region = (size_t)cc[ci] * MSLOTS * 2 + (size_t)cc[ci] * HDIM * 4 * kk[ci];
      size_t qfb = (size_t)NROWS * HDIM * 4;
      if (region < qfb) region = qfb;
      if (fixed + region <= ws_size) { chunk = cc[ci]; ksplit = kk[ci]; break; }
    }
  }
  float* qf = (float*)(ws + fixed);
  bf16_t* P = (bf16_t*)(ws + fixed);
  float* part = (float*)(ws + fixed + (size_t)chunk * MSLOTS * 2);
  const size_t partStride = (size_t)chunk * HDIM;

  // ---- stage 0: dtype prep + slot compaction ----
  init_compact<<<MSLOTS / 256, 256, 0, stream>>>(smalls, cmask);
  cvt_f32_bf16<<<(NROWS * HDIM / 8 + 255) / 256, 256, 0, stream>>>(hs, hsb, NROWS * HDIM / 8);
  cvt_f32_bf16<<<(HDIM * HDIM / 8 + 255) / 256, 256, 0, stream>>>(Wk, Wkb, HDIM * HDIM / 8);
  cvt_f32_bf16<<<(HDIM * HDIM / 8 + 255) / 256, 256, 0, stream>>>(Wo, Wob, HDIM * HDIM / 8);
  normalize_gather_mk<<<MSLOTS, 256, 0, stream>>>(mk, usage, cmkn, posmap, cmask, smalls);
  finalize_count<<<1, 1, 0, stream>>>(smalls);
  pad_zero_cmkn<<<512, 256, 0, stream>>>(smalls, cmkn);
  transpose_gather<<<dim3(HDIM / 32, MSLOTS / 32), 256, 0, stream>>>(mv, posmap, smalls, cVt);

  // ---- stage 1: q = hs @ Wk^T + bk (fp32), then normalize -> qn bf16 ----
  gemm_bt<0><<<dim3(HDIM / 128, NROWS / 128), 256, 0, stream>>>(
      hsb, Wkb, HDIM, HDIM, HDIM, bk, nullptr, nullptr, qf, nullptr, 0, smalls, 1);
  normalize_rows<<<NROWS, 256, 0, stream>>>(qf, qnb);

  // ---- stage 2/3: P = exp(10 * qn@cmkn^T) masked (+row sums); retr = P@V / den ----
  for (int c = 0; c < NROWS; c += chunk) {
    zero_f32<<<(chunk + 255) / 256, 256, 0, stream>>>(den, chunk);
    gemm_bt<1><<<dim3(MSLOTS / 128, chunk / 128), 256, 0, stream>>>(
        qnb + (size_t)c * HDIM, cmkn, HDIM, HDIM, MSLOTS, nullptr, cmask, den, nullptr, P, 0,
        smalls, 1);
    gemm_bt<3><<<dim3(HDIM / 128, chunk / 128, ksplit), 256, 0, stream>>>(
        P, cVt, MSLOTS, 0, HDIM, nullptr, nullptr, nullptr, part, nullptr, partStride, smalls,
        ksplit);
    reduce_scale<<<(chunk * HDIM / 4 + 255) / 256, 256, 0, stream>>>(
        part, partStride, ksplit, den, retrb + (size_t)c * HDIM, chunk * HDIM / 4);
  }

  // ---- stage 4: out = retrieved @ Wo^T + bo (fp32) ----
  gemm_bt<0><<<dim3(HDIM / 128, NROWS / 128), 256, 0, stream>>>(
      retrb, Wob, HDIM, HDIM, HDIM, bo, nullptr, nullptr, out, nullptr, 0, smalls, 1);
}

// Round 5
// 1039.618 us; speedup vs baseline: 1.4440x; 1.1346x over previous
//
#include <hip/hip_runtime.h>
#include <hip/hip_bf16.h>
#include <stdint.h>
#include <stddef.h>

typedef __bf16 bf16_t;
typedef __attribute__((ext_vector_type(8))) __bf16 bf16x8;
typedef __attribute__((ext_vector_type(4))) __bf16 bf16x4;
typedef __attribute__((ext_vector_type(4))) float f32x4;

#define HDIM 1024
#define MSLOTS 16384
#define NROWS 8192  // B*S
#define KSPL 8      // split-K factor for the PV GEMM (atomic accumulate)

__device__ __forceinline__ void load16_lds(const void* g, void* l) {
  __builtin_amdgcn_global_load_lds((const __attribute__((address_space(1))) void*)g,
                                   (__attribute__((address_space(3))) void*)l, 16, 0, 0);
}

// zero the compacted mask
__global__ void init_compact(int* __restrict__ cmask) {
  int i = blockIdx.x * blockDim.x + threadIdx.x;
  if (i < MSLOTS) cmask[i] = 0;
}

// Single-block deterministic compaction: posmap[pos] = slot for used slots (sorted),
// cmask[pos] = 1, smalls[0] = count, smalls[1] = count padded to mult of 512.
__global__ void compact_scan(const int* __restrict__ usage, int* __restrict__ posmap,
                             int* __restrict__ cmask, int* __restrict__ smalls) {
  __shared__ int wtot[16], wbase[16];
  const int t = threadIdx.x;          // 0..1023
  const int lane = t & 63, wid = t >> 6;
  const int base = t * 16;
  unsigned mask = 0;
  int c = 0;
  #pragma unroll
  for (int i = 0; i < 16; ++i) {
    if (usage[base + i] > 0) { mask |= (1u << i); ++c; }
  }
  int inc = c;
  #pragma unroll
  for (int d = 1; d < 64; d <<= 1) {
    int n = __shfl_up(inc, d);
    if (lane >= d) inc += n;
  }
  if (lane == 63) wtot[wid] = inc;
  __syncthreads();
  if (t == 0) {
    int acc = 0;
    #pragma unroll
    for (int w = 0; w < 16; ++w) { wbase[w] = acc; acc += wtot[w]; }
    smalls[0] = acc;
    smalls[1] = ((acc + 511) >> 9) << 9;
  }
  __syncthreads();
  int pos = wbase[wid] + inc - c;
  #pragma unroll
  for (int i = 0; i < 16; ++i) {
    if ((mask >> i) & 1u) {
      posmap[pos] = base + i;
      cmask[pos] = 1;
      ++pos;
    }
  }
}

// fp32 -> bf16 convert, 8 elems/thread
__global__ void cvt_f32_bf16(const float* __restrict__ X, bf16_t* __restrict__ Y, int n8) {
  int i = blockIdx.x * blockDim.x + threadIdx.x;
  if (i >= n8) return;
  float4 a = ((const float4*)X)[2 * i];
  float4 b = ((const float4*)X)[2 * i + 1];
  bf16x8 o;
  o[0] = (bf16_t)a.x; o[1] = (bf16_t)a.y; o[2] = (bf16_t)a.z; o[3] = (bf16_t)a.w;
  o[4] = (bf16_t)b.x; o[5] = (bf16_t)b.y; o[6] = (bf16_t)b.z; o[7] = (bf16_t)b.w;
  ((bf16x8*)Y)[i] = o;
}

// L2-normalize rows of length 1024, fp32 in -> bf16 out (for q)
__global__ void normalize_rows(const float* __restrict__ X, bf16_t* __restrict__ Y) {
  __shared__ float part[4];
  const int t = threadIdx.x;
  const size_t row = blockIdx.x;
  float4 v = ((const float4*)(X + row * 1024))[t];
  float s = v.x * v.x + v.y * v.y + v.z * v.z + v.w * v.w;
  #pragma unroll
  for (int m = 32; m >= 1; m >>= 1) s += __shfl_xor(s, m);
  if ((t & 63) == 0) part[t >> 6] = s;
  __syncthreads();
  float tot = part[0] + part[1] + part[2] + part[3];
  float r = rsqrtf(tot + 1e-6f);
  bf16x4 o;
  o[0] = (bf16_t)(v.x * r); o[1] = (bf16_t)(v.y * r);
  o[2] = (bf16_t)(v.z * r); o[3] = (bf16_t)(v.w * r);
  *(bf16x4*)&Y[row * 1024 + t * 4] = o;
}

// cmkn[p] = normalize(mk[posmap[p]]) for p<cnt; zeros for cnt<=p<mpad. No atomics.
__global__ void normalize_gather(const float* __restrict__ mk, const int* __restrict__ posmap,
                                 const int* __restrict__ smalls, bf16_t* __restrict__ cmkn) {
  __shared__ float part[4];
  const int p = blockIdx.x;
  const int cnt = smalls[0], mpad = smalls[1];
  if (p >= mpad) return;
  const int t = threadIdx.x;
  if (p >= cnt) {
    bf16x4 z;
    z[0] = z[1] = z[2] = z[3] = (bf16_t)0.f;
    *(bf16x4*)&cmkn[(size_t)p * 1024 + t * 4] = z;
    return;
  }
  const int slot = posmap[p];
  float4 v = ((const float4*)(mk + (size_t)slot * 1024))[t];
  float s = v.x * v.x + v.y * v.y + v.z * v.z + v.w * v.w;
  #pragma unroll
  for (int m = 32; m >= 1; m >>= 1) s += __shfl_xor(s, m);
  if ((t & 63) == 0) part[t >> 6] = s;
  __syncthreads();
  float tot = part[0] + part[1] + part[2] + part[3];
  float r = rsqrtf(tot + 1e-6f);
  bf16x4 o;
  o[0] = (bf16_t)(v.x * r); o[1] = (bf16_t)(v.y * r);
  o[2] = (bf16_t)(v.z * r); o[3] = (bf16_t)(v.w * r);
  *(bf16x4*)&cmkn[(size_t)p * 1024 + t * 4] = o;
}

// cVt[h][pos] = pos<cnt ? mv[posmap[pos]][h] : 0, for pos < mpad
__global__ void transpose_gather(const float* __restrict__ mv, const int* __restrict__ posmap,
                                 const int* __restrict__ smalls, bf16_t* __restrict__ cVt) {
  __shared__ float tile[32][33];
  const int cnt = smalls[0], mpad = smalls[1];
  const int p0 = blockIdx.y * 32;
  if (p0 >= mpad) return;
  const int tx = threadIdx.x & 31, ty = threadIdx.x >> 5;  // 32 x 8
  const int h0 = blockIdx.x * 32;
  #pragma unroll
  for (int j = 0; j < 32; j += 8) {
    const int pos = p0 + ty + j;
    float val = 0.f;
    if (pos < cnt) val = mv[(size_t)posmap[pos] * 1024 + h0 + tx];
    tile[ty + j][tx] = val;
  }
  __syncthreads();
  #pragma unroll
  for (int j = 0; j < 32; j += 8)
    cVt[(size_t)(h0 + ty + j) * MSLOTS + p0 + tx] = (bf16_t)tile[tx][ty + j];
}

__global__ void zero_f32(float* __restrict__ p, int n4) {
  int i = blockIdx.x * blockDim.x + threadIdx.x;
  if (i < n4) ((float4*)p)[i] = (float4){0.f, 0.f, 0.f, 0.f};
}

// out = retrf * (1/den[row]) -> bf16, 4 elems/thread
__global__ void scale_cvt(const float* __restrict__ retrf, const float* __restrict__ den,
                          bf16_t* __restrict__ out, int n4) {
  int i = blockIdx.x * blockDim.x + threadIdx.x;
  if (i >= n4) return;
  float4 s = ((const float4*)retrf)[i];
  const int row = (i * 4) >> 10;  // HDIM=1024
  const float r = 1.0f / den[row];
  bf16x4 o;
  o[0] = (bf16_t)(s.x * r); o[1] = (bf16_t)(s.y * r);
  o[2] = (bf16_t)(s.z * r); o[3] = (bf16_t)(s.w * r);
  ((bf16x4*)out)[i] = o;
}

// m97-style 128x128 bf16 GEMM, C = A * Bt^T. A:[rows,ldk], Bt:[N,ldk] row-major.
// EPI 0: outf = acc + bias[col]                                   (fp32 out)
// EPI 1: outb = cmask[col] ? exp(10*acc) : 0 (bf16) + atomic row-sums into den;
//        x-blocks beyond mpad exit
// EPI 3: split-K over K=mpad (device): atomicAdd(outf, acc)       (fp32 accumulate)
template <int EPI>
__global__ void gemm_bt(const bf16_t* __restrict__ A, const bf16_t* __restrict__ Bt,
                        int ldk, int kLenIn, int ldc,
                        const float* __restrict__ bias,
                        const int* __restrict__ cmask,
                        float* __restrict__ den,
                        float* __restrict__ outf, bf16_t* __restrict__ outb,
                        const int* __restrict__ smalls, int ks) {
  __shared__ bf16_t lA[128 * 32];
  __shared__ bf16_t lB[128 * 32];
  const int t = threadIdx.x;
  const int lane = t & 63;
  const int wave = t >> 6;
  const int wm = (wave >> 1) << 6;  // wave tile origin (2x2 waves of 64x64)
  const int wn = (wave & 1) << 6;
  const int lr = lane & 15;
  const int lq = lane >> 4;

  int kLen = kLenIn;
  int kstart = 0;
  if (EPI == 1) {
    if (blockIdx.x * 128 >= smalls[1]) return;  // compacted N bound (block-uniform)
  }
  if (EPI == 3) {
    kLen = smalls[1] / ks;  // mpad % 512 == 0 -> kLen % 32 == 0 for ks in {8,16}
    kstart = blockIdx.z * kLen;
  }

  // Tile staging: 128 rows x 32 K-cols = 8192 B per array; 256 thr x 16 B = half,
  // so each thread issues TWO global_load_lds per array (rows 0-63 and 64-127).
  const int r0 = t >> 2;         // 0..63
  const int c0 = (t & 3) * 8;    // 0,8,16,24
  const bf16_t* pA0 = A + (size_t)(blockIdx.y * 128 + r0) * ldk + kstart + c0;
  const bf16_t* pA1 = pA0 + (size_t)64 * ldk;
  const bf16_t* pB0 = Bt + (size_t)(blockIdx.x * 128 + r0) * ldk + kstart + c0;
  const bf16_t* pB1 = pB0 + (size_t)64 * ldk;

  f32x4 acc[4][4];
  #pragma unroll
  for (int i = 0; i < 4; ++i)
    #pragma unroll
    for (int j = 0; j < 4; ++j) acc[i][j] = (f32x4){0.f, 0.f, 0.f, 0.f};

  for (int k0 = 0; k0 < kLen; k0 += 32) {
    __syncthreads();
    load16_lds(pA0, &lA[t * 8]);
    load16_lds(pA1, &lA[2048 + t * 8]);
    load16_lds(pB0, &lB[t * 8]);
    load16_lds(pB1, &lB[2048 + t * 8]);
    pA0 += 32; pA1 += 32; pB0 += 32; pB1 += 32;
    __syncthreads();
    bf16x8 af[4], bfr[4];
    #pragma unroll
    for (int i = 0; i < 4; ++i)
      af[i] = *(const bf16x8*)&lA[(wm + i * 16 + lr) * 32 + lq * 8];
    #pragma unroll
    for (int j = 0; j < 4; ++j)
      bfr[j] = *(const bf16x8*)&lB[(wn + j * 16 + lr) * 32 + lq * 8];
    #pragma unroll
    for (int i = 0; i < 4; ++i)
      #pragma unroll
      for (int j = 0; j < 4; ++j)
        acc[i][j] = __builtin_amdgcn_mfma_f32_16x16x32_bf16(af[i], bfr[j], acc[i][j], 0, 0, 0);
  }

  // C/D layout (m89-verified): col = lane&15, row = (lane>>4)*4 + r
  const int colBase = blockIdx.x * 128 + wn + lr;
  const int rowBase = blockIdx.y * 128 + wm + lq * 4;

  float rs[4][4];  // per-(i,r) row-sum accumulators (EPI==1)
  if (EPI == 1) {
    #pragma unroll
    for (int i = 0; i < 4; ++i)
      #pragma unroll
      for (int r = 0; r < 4; ++r) rs[i][r] = 0.f;
  }

  #pragma unroll
  for (int j = 0; j < 4; ++j) {
    const int col = colBase + j * 16;
    float bval = 0.f;
    bool ok = true;
    if (EPI == 0) bval = bias[col];
    if (EPI == 1) ok = cmask[col] > 0;
    #pragma unroll
    for (int i = 0; i < 4; ++i) {
      const int row = rowBase + i * 16;
      #pragma unroll
      for (int r = 0; r < 4; ++r) {
        const size_t idx = (size_t)(row + r) * ldc + col;
        float v = acc[i][j][r];
        if (EPI == 0) outf[idx] = v + bval;
        if (EPI == 1) {
          float e = ok ? exp2f(v * 14.426950408889634f) : 0.f;
          rs[i][r] += e;
          outb[idx] = (bf16_t)e;
        }
        if (EPI == 3) atomicAdd(&outf[idx], v);
      }
    }
  }

  if (EPI == 1) {
    // reduce rs over the 16-lane col group (lr), then one atomic per row per wave
    #pragma unroll
    for (int i = 0; i < 4; ++i)
      #pragma unroll
      for (int r = 0; r < 4; ++r) {
        float s = rs[i][r];
        s += __shfl_xor(s, 1);
        s += __shfl_xor(s, 2);
        s += __shfl_xor(s, 4);
        s += __shfl_xor(s, 8);
        if (lr == 0) atomicAdd(&den[rowBase + i * 16 + r], s);
      }
  }
}

extern "C" void kernel_launch(void* const* d_in, const int* in_sizes, int n_in,
                              void* d_out, int out_size, void* d_ws, size_t ws_size,
                              hipStream_t stream) {
  const float* hs = (const float*)d_in[0];
  const float* Wk = (const float*)d_in[1];
  const float* bk = (const float*)d_in[2];
  // d_in[3]=Wv, d_in[4]=bv are unused by the reference
  const float* Wo = (const float*)d_in[5];
  const float* bo = (const float*)d_in[6];
  const float* mk = (const float*)d_in[7];
  const float* mv = (const float*)d_in[8];
  const int* usage = (const int*)d_in[9];
  float* out = (float*)d_out;

  char* ws = (char*)d_ws;
  size_t off = 0;
  auto alloc = [&](size_t b) -> void* {
    void* p = ws + off;
    off += (b + 255) & ~(size_t)255;
    return p;
  };
  // Persistent buffers (live across the chunk loop)
  bf16_t* cmkn = (bf16_t*)alloc((size_t)MSLOTS * HDIM * 2);
  bf16_t* cVt = (bf16_t*)alloc((size_t)HDIM * MSLOTS * 2);
  bf16_t* qnb = (bf16_t*)alloc((size_t)NROWS * HDIM * 2);
  bf16_t* retrb = (bf16_t*)alloc((size_t)NROWS * HDIM * 2);
  bf16_t* Wob = (bf16_t*)alloc((size_t)HDIM * HDIM * 2);
  float* den = (float*)alloc((size_t)NROWS * 4);
  int* posmap = (int*)alloc((size_t)MSLOTS * 4);
  int* cmask = (int*)alloc((size_t)MSLOTS * 4);
  int* smalls = (int*)alloc(256 * 4);
  const size_t fixed = off;

  // Overlay region: phase A = [hsb][Wkb][qf] (dead after stage 1);
  // loop = [P chunk][retrf]. Pick the largest chunk that fits.
  int chunk = 128;
  {
    const int cc[7] = {8192, 4096, 2048, 1024, 512, 256, 128};
    for (int ci = 0; ci < 7; ++ci) {
      size_t region = (size_t)cc[ci] * (MSLOTS * 2 + HDIM * 4);
      size_t phaseA = (size_t)NROWS * HDIM * 2 + (size_t)HDIM * HDIM * 2 +
                      (size_t)NROWS * HDIM * 4 + 1024;
      if (region < phaseA) region = phaseA;
      if (fixed + region <= ws_size) { chunk = cc[ci]; break; }
    }
  }
  bf16_t* hsb = (bf16_t*)(ws + fixed);
  bf16_t* Wkb = (bf16_t*)(ws + fixed + (size_t)NROWS * HDIM * 2);
  float* qf = (float*)(ws + fixed + (size_t)NROWS * HDIM * 2 + (size_t)HDIM * HDIM * 2);
  bf16_t* P = (bf16_t*)(ws + fixed);
  float* retrf = (float*)(ws + fixed + (size_t)chunk * MSLOTS * 2);

  // ---- stage 0: compaction + dtype prep ----
  init_compact<<<MSLOTS / 256, 256, 0, stream>>>(cmask);
  compact_scan<<<1, 1024, 0, stream>>>(usage, posmap, cmask, smalls);
  cvt_f32_bf16<<<(NROWS * HDIM / 8 + 255) / 256, 256, 0, stream>>>(hs, hsb, NROWS * HDIM / 8);
  cvt_f32_bf16<<<(HDIM * HDIM / 8 + 255) / 256, 256, 0, stream>>>(Wk, Wkb, HDIM * HDIM / 8);
  cvt_f32_bf16<<<(HDIM * HDIM / 8 + 255) / 256, 256, 0, stream>>>(Wo, Wob, HDIM * HDIM / 8);
  normalize_gather<<<MSLOTS, 256, 0, stream>>>(mk, posmap, smalls, cmkn);
  transpose_gather<<<dim3(HDIM / 32, MSLOTS / 32), 256, 0, stream>>>(mv, posmap, smalls, cVt);

  // ---- stage 1: q = hs @ Wk^T + bk (fp32), then normalize -> qn bf16 ----
  gemm_bt<0><<<dim3(HDIM / 128, NROWS / 128), 256, 0, stream>>>(
      hsb, Wkb, HDIM, HDIM, HDIM, bk, nullptr, nullptr, qf, nullptr, smalls, 1);
  normalize_rows<<<NROWS, 256, 0, stream>>>(qf, qnb);

  // ---- stage 2/3: P = exp(10 * qn@cmkn^T) masked (+row sums); retr = P@V / den ----
  for (int c = 0; c < NROWS; c += chunk) {
    zero_f32<<<(chunk / 4 + 255) / 256, 256, 0, stream>>>(den, chunk / 4);
    zero_f32<<<(chunk * HDIM / 4 + 255) / 256, 256, 0, stream>>>(retrf, chunk * HDIM / 4);
    gemm_bt<1><<<dim3(MSLOTS / 128, chunk / 128), 256, 0, stream>>>(
        qnb + (size_t)c * HDIM, cmkn, HDIM, HDIM, MSLOTS, nullptr, cmask, den, nullptr, P,
        smalls, 1);
    gemm_bt<3><<<dim3(HDIM / 128, chunk / 128, KSPL), 256, 0, stream>>>(
        P, cVt, MSLOTS, 0, HDIM, nullptr, nullptr, nullptr, retrf, nullptr, smalls, KSPL);
    scale_cvt<<<(chunk * HDIM / 4 + 255) / 256, 256, 0, stream>>>(
        retrf, den, retrb + (size_t)c * HDIM, chunk * HDIM / 4);
  }

  // ---- stage 4: out = retrieved @ Wo^T + bo (fp32) ----
  gemm_bt<0><<<dim3(HDIM / 128, NROWS / 128), 256, 0, stream>>>(
      retrb, Wob, HDIM, HDIM, HDIM, bo, nullptr, nullptr, out, nullptr, smalls, 1);
}

// Round 6
// 963.506 us; speedup vs baseline: 1.5581x; 1.0790x over previous
//
#include <hip/hip_runtime.h>
#include <hip/hip_bf16.h>
#include <stdint.h>
#include <stddef.h>

typedef __bf16 bf16_t;
typedef __attribute__((ext_vector_type(8))) __bf16 bf16x8;
typedef __attribute__((ext_vector_type(4))) __bf16 bf16x4;
typedef __attribute__((ext_vector_type(4))) float f32x4;

#define HDIM 1024
#define MSLOTS 16384
#define NROWS 8192  // B*S
#define KSPL 8      // split-K factor for the PV GEMM (atomic accumulate)

__device__ __forceinline__ void load16_lds(const void* g, void* l) {
  __builtin_amdgcn_global_load_lds((const __attribute__((address_space(1))) void*)g,
                                   (__attribute__((address_space(3))) void*)l, 16, 0, 0);
}

// zero the compacted mask
__global__ void init_compact(int* __restrict__ cmask) {
  int i = blockIdx.x * blockDim.x + threadIdx.x;
  if (i < MSLOTS) cmask[i] = 0;
}

// Single-block deterministic compaction: posmap[pos] = slot for used slots (sorted),
// cmask[pos] = 1, smalls[0] = count, smalls[1] = count padded to mult of 512.
__global__ void compact_scan(const int* __restrict__ usage, int* __restrict__ posmap,
                             int* __restrict__ cmask, int* __restrict__ smalls) {
  __shared__ int wtot[16], wbase[16];
  const int t = threadIdx.x;          // 0..1023
  const int lane = t & 63, wid = t >> 6;
  const int base = t * 16;
  unsigned mask = 0;
  int c = 0;
  #pragma unroll
  for (int i = 0; i < 16; ++i) {
    if (usage[base + i] > 0) { mask |= (1u << i); ++c; }
  }
  int inc = c;
  #pragma unroll
  for (int d = 1; d < 64; d <<= 1) {
    int n = __shfl_up(inc, d);
    if (lane >= d) inc += n;
  }
  if (lane == 63) wtot[wid] = inc;
  __syncthreads();
  if (t == 0) {
    int acc = 0;
    #pragma unroll
    for (int w = 0; w < 16; ++w) { wbase[w] = acc; acc += wtot[w]; }
    smalls[0] = acc;
    smalls[1] = ((acc + 511) >> 9) << 9;
  }
  __syncthreads();
  int pos = wbase[wid] + inc - c;
  #pragma unroll
  for (int i = 0; i < 16; ++i) {
    if ((mask >> i) & 1u) {
      posmap[pos] = base + i;
      cmask[pos] = 1;
      ++pos;
    }
  }
}

// fp32 -> bf16 convert, 8 elems/thread
__global__ void cvt_f32_bf16(const float* __restrict__ X, bf16_t* __restrict__ Y, int n8) {
  int i = blockIdx.x * blockDim.x + threadIdx.x;
  if (i >= n8) return;
  float4 a = ((const float4*)X)[2 * i];
  float4 b = ((const float4*)X)[2 * i + 1];
  bf16x8 o;
  o[0] = (bf16_t)a.x; o[1] = (bf16_t)a.y; o[2] = (bf16_t)a.z; o[3] = (bf16_t)a.w;
  o[4] = (bf16_t)b.x; o[5] = (bf16_t)b.y; o[6] = (bf16_t)b.z; o[7] = (bf16_t)b.w;
  ((bf16x8*)Y)[i] = o;
}

// L2-normalize rows of length 1024, fp32 in -> bf16 out (for q)
__global__ void normalize_rows(const float* __restrict__ X, bf16_t* __restrict__ Y) {
  __shared__ float part[4];
  const int t = threadIdx.x;
  const size_t row = blockIdx.x;
  float4 v = ((const float4*)(X + row * 1024))[t];
  float s = v.x * v.x + v.y * v.y + v.z * v.z + v.w * v.w;
  #pragma unroll
  for (int m = 32; m >= 1; m >>= 1) s += __shfl_xor(s, m);
  if ((t & 63) == 0) part[t >> 6] = s;
  __syncthreads();
  float tot = part[0] + part[1] + part[2] + part[3];
  float r = rsqrtf(tot + 1e-6f);
  bf16x4 o;
  o[0] = (bf16_t)(v.x * r); o[1] = (bf16_t)(v.y * r);
  o[2] = (bf16_t)(v.z * r); o[3] = (bf16_t)(v.w * r);
  *(bf16x4*)&Y[row * 1024 + t * 4] = o;
}

// cmkn[p] = normalize(mk[posmap[p]]) for p<cnt; zeros for cnt<=p<mpad. No atomics.
__global__ void normalize_gather(const float* __restrict__ mk, const int* __restrict__ posmap,
                                 const int* __restrict__ smalls, bf16_t* __restrict__ cmkn) {
  __shared__ float part[4];
  const int p = blockIdx.x;
  const int cnt = smalls[0], mpad = smalls[1];
  if (p >= mpad) return;
  const int t = threadIdx.x;
  if (p >= cnt) {
    bf16x4 z;
    z[0] = z[1] = z[2] = z[3] = (bf16_t)0.f;
    *(bf16x4*)&cmkn[(size_t)p * 1024 + t * 4] = z;
    return;
  }
  const int slot = posmap[p];
  float4 v = ((const float4*)(mk + (size_t)slot * 1024))[t];
  float s = v.x * v.x + v.y * v.y + v.z * v.z + v.w * v.w;
  #pragma unroll
  for (int m = 32; m >= 1; m >>= 1) s += __shfl_xor(s, m);
  if ((t & 63) == 0) part[t >> 6] = s;
  __syncthreads();
  float tot = part[0] + part[1] + part[2] + part[3];
  float r = rsqrtf(tot + 1e-6f);
  bf16x4 o;
  o[0] = (bf16_t)(v.x * r); o[1] = (bf16_t)(v.y * r);
  o[2] = (bf16_t)(v.z * r); o[3] = (bf16_t)(v.w * r);
  *(bf16x4*)&cmkn[(size_t)p * 1024 + t * 4] = o;
}

// cVt[h][pos] = pos<cnt ? mv[posmap[pos]][h] : 0, for pos < mpad
__global__ void transpose_gather(const float* __restrict__ mv, const int* __restrict__ posmap,
                                 const int* __restrict__ smalls, bf16_t* __restrict__ cVt) {
  __shared__ float tile[32][33];
  const int cnt = smalls[0], mpad = smalls[1];
  const int p0 = blockIdx.y * 32;
  if (p0 >= mpad) return;
  const int tx = threadIdx.x & 31, ty = threadIdx.x >> 5;  // 32 x 8
  const int h0 = blockIdx.x * 32;
  #pragma unroll
  for (int j = 0; j < 32; j += 8) {
    const int pos = p0 + ty + j;
    float val = 0.f;
    if (pos < cnt) val = mv[(size_t)posmap[pos] * 1024 + h0 + tx];
    tile[ty + j][tx] = val;
  }
  __syncthreads();
  #pragma unroll
  for (int j = 0; j < 32; j += 8)
    cVt[(size_t)(h0 + ty + j) * MSLOTS + p0 + tx] = (bf16_t)tile[tx][ty + j];
}

__global__ void zero_f32(float* __restrict__ p, int n4) {
  int i = blockIdx.x * blockDim.x + threadIdx.x;
  if (i < n4) ((float4*)p)[i] = (float4){0.f, 0.f, 0.f, 0.f};
}

// out = retrf * (1/den[row]) -> bf16, 4 elems/thread
__global__ void scale_cvt(const float* __restrict__ retrf, const float* __restrict__ den,
                          bf16_t* __restrict__ out, int n4) {
  int i = blockIdx.x * blockDim.x + threadIdx.x;
  if (i >= n4) return;
  float4 s = ((const float4*)retrf)[i];
  const int row = (i * 4) >> 10;  // HDIM=1024
  const float r = 1.0f / den[row];
  bf16x4 o;
  o[0] = (bf16_t)(s.x * r); o[1] = (bf16_t)(s.y * r);
  o[2] = (bf16_t)(s.z * r); o[3] = (bf16_t)(s.w * r);
  ((bf16x4*)out)[i] = o;
}

// m97-style 128x128 bf16 GEMM, C = A * Bt^T. A:[rows,ldk], Bt:[N,ldk] row-major.
// EPI 0: outf = acc + bias[col]                                   (fp32 out)
// EPI 1: outb = cmask[col] ? exp(10*acc) : 0 (bf16) + atomic row-sums into den;
//        x-blocks beyond mpad exit
// EPI 3: split-K over K=mpad (device): atomicAdd(outf, acc)       (fp32 accumulate)
//        + XCD-aware block swizzle: y%8 fastest (-> XCD via round-robin), then x,
//        then y/8, then z. Gives each XCD an L2-resident A working set and 8-wide
//        A-tile reuse across its consecutive blocks.
template <int EPI>
__global__ void gemm_bt(const bf16_t* __restrict__ A, const bf16_t* __restrict__ Bt,
                        int ldk, int kLenIn, int ldc,
                        const float* __restrict__ bias,
                        const int* __restrict__ cmask,
                        float* __restrict__ den,
                        float* __restrict__ outf, bf16_t* __restrict__ outb,
                        const int* __restrict__ smalls, int ks) {
  __shared__ bf16_t lA[128 * 32];
  __shared__ bf16_t lB[128 * 32];
  const int t = threadIdx.x;
  const int lane = t & 63;
  const int wave = t >> 6;
  const int wm = (wave >> 1) << 6;  // wave tile origin (2x2 waves of 64x64)
  const int wn = (wave & 1) << 6;
  const int lr = lane & 15;
  const int lq = lane >> 4;

  int bx = blockIdx.x, by = blockIdx.y, bz = blockIdx.z;
  int kLen = kLenIn;
  int kstart = 0;
  if (EPI == 1) {
    if (bx * 128 >= smalls[1]) return;  // compacted N bound (block-uniform)
  }
  if (EPI == 3) {
    const unsigned nx = gridDim.x, ny = gridDim.y;
    if ((ny & 7u) == 0u) {
      unsigned lin = blockIdx.x + nx * (blockIdx.y + ny * blockIdx.z);
      unsigned ylow = lin & 7u;
      unsigned rest = lin >> 3;
      bx = rest % nx;
      unsigned rest2 = rest / nx;
      unsigned yhigh = rest2 % (ny >> 3);
      bz = rest2 / (ny >> 3);
      by = ylow + 8u * yhigh;
    }
    kLen = smalls[1] / ks;  // mpad % 512 == 0 -> kLen % 32 == 0 for ks in {8,16}
    kstart = bz * kLen;
  }

  // Tile staging: 128 rows x 32 K-cols = 8192 B per array; 256 thr x 16 B = half,
  // so each thread issues TWO global_load_lds per array (rows 0-63 and 64-127).
  const int r0 = t >> 2;         // 0..63
  const int c0 = (t & 3) * 8;    // 0,8,16,24
  const bf16_t* pA0 = A + (size_t)(by * 128 + r0) * ldk + kstart + c0;
  const bf16_t* pA1 = pA0 + (size_t)64 * ldk;
  const bf16_t* pB0 = Bt + (size_t)(bx * 128 + r0) * ldk + kstart + c0;
  const bf16_t* pB1 = pB0 + (size_t)64 * ldk;

  f32x4 acc[4][4];
  #pragma unroll
  for (int i = 0; i < 4; ++i)
    #pragma unroll
    for (int j = 0; j < 4; ++j) acc[i][j] = (f32x4){0.f, 0.f, 0.f, 0.f};

  for (int k0 = 0; k0 < kLen; k0 += 32) {
    __syncthreads();
    load16_lds(pA0, &lA[t * 8]);
    load16_lds(pA1, &lA[2048 + t * 8]);
    load16_lds(pB0, &lB[t * 8]);
    load16_lds(pB1, &lB[2048 + t * 8]);
    pA0 += 32; pA1 += 32; pB0 += 32; pB1 += 32;
    __syncthreads();
    bf16x8 af[4], bfr[4];
    #pragma unroll
    for (int i = 0; i < 4; ++i)
      af[i] = *(const bf16x8*)&lA[(wm + i * 16 + lr) * 32 + lq * 8];
    #pragma unroll
    for (int j = 0; j < 4; ++j)
      bfr[j] = *(const bf16x8*)&lB[(wn + j * 16 + lr) * 32 + lq * 8];
    #pragma unroll
    for (int i = 0; i < 4; ++i)
      #pragma unroll
      for (int j = 0; j < 4; ++j)
        acc[i][j] = __builtin_amdgcn_mfma_f32_16x16x32_bf16(af[i], bfr[j], acc[i][j], 0, 0, 0);
  }

  // C/D layout (m89-verified): col = lane&15, row = (lane>>4)*4 + r
  const int colBase = bx * 128 + wn + lr;
  const int rowBase = by * 128 + wm + lq * 4;

  float rs[4][4];  // per-(i,r) row-sum accumulators (EPI==1)
  if (EPI == 1) {
    #pragma unroll
    for (int i = 0; i < 4; ++i)
      #pragma unroll
      for (int r = 0; r < 4; ++r) rs[i][r] = 0.f;
  }

  #pragma unroll
  for (int j = 0; j < 4; ++j) {
    const int col = colBase + j * 16;
    float bval = 0.f;
    bool ok = true;
    if (EPI == 0) bval = bias[col];
    if (EPI == 1) ok = cmask[col] > 0;
    #pragma unroll
    for (int i = 0; i < 4; ++i) {
      const int row = rowBase + i * 16;
      #pragma unroll
      for (int r = 0; r < 4; ++r) {
        const size_t idx = (size_t)(row + r) * ldc + col;
        float v = acc[i][j][r];
        if (EPI == 0) outf[idx] = v + bval;
        if (EPI == 1) {
          float e = ok ? exp2f(v * 14.426950408889634f) : 0.f;
          rs[i][r] += e;
          outb[idx] = (bf16_t)e;
        }
        if (EPI == 3) atomicAdd(&outf[idx], v);
      }
    }
  }

  if (EPI == 1) {
    // reduce rs over the 16-lane col group (lr), then one atomic per row per wave
    #pragma unroll
    for (int i = 0; i < 4; ++i)
      #pragma unroll
      for (int r = 0; r < 4; ++r) {
        float s = rs[i][r];
        s += __shfl_xor(s, 1);
        s += __shfl_xor(s, 2);
        s += __shfl_xor(s, 4);
        s += __shfl_xor(s, 8);
        if (lr == 0) atomicAdd(&den[rowBase + i * 16 + r], s);
      }
  }
}

extern "C" void kernel_launch(void* const* d_in, const int* in_sizes, int n_in,
                              void* d_out, int out_size, void* d_ws, size_t ws_size,
                              hipStream_t stream) {
  const float* hs = (const float*)d_in[0];
  const float* Wk = (const float*)d_in[1];
  const float* bk = (const float*)d_in[2];
  // d_in[3]=Wv, d_in[4]=bv are unused by the reference
  const float* Wo = (const float*)d_in[5];
  const float* bo = (const float*)d_in[6];
  const float* mk = (const float*)d_in[7];
  const float* mv = (const float*)d_in[8];
  const int* usage = (const int*)d_in[9];
  float* out = (float*)d_out;

  char* ws = (char*)d_ws;
  size_t off = 0;
  auto alloc = [&](size_t b) -> void* {
    void* p = ws + off;
    off += (b + 255) & ~(size_t)255;
    return p;
  };
  // Persistent buffers (live across the chunk loop)
  bf16_t* cmkn = (bf16_t*)alloc((size_t)MSLOTS * HDIM * 2);
  bf16_t* cVt = (bf16_t*)alloc((size_t)HDIM * MSLOTS * 2);
  bf16_t* qnb = (bf16_t*)alloc((size_t)NROWS * HDIM * 2);
  bf16_t* retrb = (bf16_t*)alloc((size_t)NROWS * HDIM * 2);
  bf16_t* Wob = (bf16_t*)alloc((size_t)HDIM * HDIM * 2);
  float* den = (float*)alloc((size_t)NROWS * 4);
  int* posmap = (int*)alloc((size_t)MSLOTS * 4);
  int* cmask = (int*)alloc((size_t)MSLOTS * 4);
  int* smalls = (int*)alloc(256 * 4);
  const size_t fixed = off;

  // Overlay region: phase A = [hsb][Wkb][qf] (dead after stage 1);
  // loop = [P chunk][retrf]. Pick the largest chunk that fits.
  int chunk = 128;
  {
    const int cc[7] = {8192, 4096, 2048, 1024, 512, 256, 128};
    for (int ci = 0; ci < 7; ++ci) {
      size_t region = (size_t)cc[ci] * (MSLOTS * 2 + HDIM * 4);
      size_t phaseA = (size_t)NROWS * HDIM * 2 + (size_t)HDIM * HDIM * 2 +
                      (size_t)NROWS * HDIM * 4 + 1024;
      if (region < phaseA) region = phaseA;
      if (fixed + region <= ws_size) { chunk = cc[ci]; break; }
    }
  }
  bf16_t* hsb = (bf16_t*)(ws + fixed);
  bf16_t* Wkb = (bf16_t*)(ws + fixed + (size_t)NROWS * HDIM * 2);
  float* qf = (float*)(ws + fixed + (size_t)NROWS * HDIM * 2 + (size_t)HDIM * HDIM * 2);
  bf16_t* P = (bf16_t*)(ws + fixed);
  float* retrf = (float*)(ws + fixed + (size_t)chunk * MSLOTS * 2);

  // ---- stage 0: compaction + dtype prep ----
  init_compact<<<MSLOTS / 256, 256, 0, stream>>>(cmask);
  compact_scan<<<1, 1024, 0, stream>>>(usage, posmap, cmask, smalls);
  cvt_f32_bf16<<<(NROWS * HDIM / 8 + 255) / 256, 256, 0, stream>>>(hs, hsb, NROWS * HDIM / 8);
  cvt_f32_bf16<<<(HDIM * HDIM / 8 + 255) / 256, 256, 0, stream>>>(Wk, Wkb, HDIM * HDIM / 8);
  cvt_f32_bf16<<<(HDIM * HDIM / 8 + 255) / 256, 256, 0, stream>>>(Wo, Wob, HDIM * HDIM / 8);
  normalize_gather<<<MSLOTS, 256, 0, stream>>>(mk, posmap, smalls, cmkn);
  transpose_gather<<<dim3(HDIM / 32, MSLOTS / 32), 256, 0, stream>>>(mv, posmap, smalls, cVt);

  // ---- stage 1: q = hs @ Wk^T + bk (fp32), then normalize -> qn bf16 ----
  gemm_bt<0><<<dim3(HDIM / 128, NROWS / 128), 256, 0, stream>>>(
      hsb, Wkb, HDIM, HDIM, HDIM, bk, nullptr, nullptr, qf, nullptr, smalls, 1);
  normalize_rows<<<NROWS, 256, 0, stream>>>(qf, qnb);

  // ---- stage 2/3: P = exp(10 * qn@cmkn^T) masked (+row sums); retr = P@V / den ----
  for (int c = 0; c < NROWS; c += chunk) {
    zero_f32<<<(chunk / 4 + 255) / 256, 256, 0, stream>>>(den, chunk / 4);
    zero_f32<<<(chunk * HDIM / 4 + 255) / 256, 256, 0, stream>>>(retrf, chunk * HDIM / 4);
    gemm_bt<1><<<dim3(MSLOTS / 128, chunk / 128), 256, 0, stream>>>(
        qnb + (size_t)c * HDIM, cmkn, HDIM, HDIM, MSLOTS, nullptr, cmask, den, nullptr, P,
        smalls, 1);
    gemm_bt<3><<<dim3(HDIM / 128, chunk / 128, KSPL), 256, 0, stream>>>(
        P, cVt, MSLOTS, 0, HDIM, nullptr, nullptr, nullptr, retrf, nullptr, smalls, KSPL);
    scale_cvt<<<(chunk * HDIM / 4 + 255) / 256, 256, 0, stream>>>(
        retrf, den, retrb + (size_t)c * HDIM, chunk * HDIM / 4);
  }

  // ---- stage 4: out = retrieved @ Wo^T + bo (fp32) ----
  gemm_bt<0><<<dim3(HDIM / 128, NROWS / 128), 256, 0, stream>>>(
      retrb, Wob, HDIM, HDIM, HDIM, bo, nullptr, nullptr, out, nullptr, smalls, 1);
}

// Round 7
// 892.597 us; speedup vs baseline: 1.6819x; 1.0794x over previous
//
#include <hip/hip_runtime.h>
#include <hip/hip_bf16.h>
#include <stdint.h>
#include <stddef.h>

typedef __bf16 bf16_t;
typedef __attribute__((ext_vector_type(8))) __bf16 bf16x8;
typedef __attribute__((ext_vector_type(4))) __bf16 bf16x4;
typedef __attribute__((ext_vector_type(4))) float f32x4;

#define HDIM 1024
#define MSLOTS 16384
#define NROWS 8192  // B*S

__device__ __forceinline__ void load16_lds(const void* g, void* l) {
  __builtin_amdgcn_global_load_lds((const __attribute__((address_space(1))) void*)g,
                                   (__attribute__((address_space(3))) void*)l, 16, 0, 0);
}

// zero the compacted mask
__global__ void init_compact(int* __restrict__ cmask) {
  int i = blockIdx.x * blockDim.x + threadIdx.x;
  if (i < MSLOTS) cmask[i] = 0;
}

// Single-block deterministic compaction: posmap[pos] = slot for used slots (sorted),
// cmask[pos] = 1, smalls[0] = count, smalls[1] = count padded to mult of 512.
__global__ void compact_scan(const int* __restrict__ usage, int* __restrict__ posmap,
                             int* __restrict__ cmask, int* __restrict__ smalls) {
  __shared__ int wtot[16], wbase[16];
  const int t = threadIdx.x;          // 0..1023
  const int lane = t & 63, wid = t >> 6;
  const int base = t * 16;
  unsigned mask = 0;
  int c = 0;
  #pragma unroll
  for (int i = 0; i < 16; ++i) {
    if (usage[base + i] > 0) { mask |= (1u << i); ++c; }
  }
  int inc = c;
  #pragma unroll
  for (int d = 1; d < 64; d <<= 1) {
    int n = __shfl_up(inc, d);
    if (lane >= d) inc += n;
  }
  if (lane == 63) wtot[wid] = inc;
  __syncthreads();
  if (t == 0) {
    int acc = 0;
    #pragma unroll
    for (int w = 0; w < 16; ++w) { wbase[w] = acc; acc += wtot[w]; }
    smalls[0] = acc;
    smalls[1] = ((acc + 511) >> 9) << 9;
  }
  __syncthreads();
  int pos = wbase[wid] + inc - c;
  #pragma unroll
  for (int i = 0; i < 16; ++i) {
    if ((mask >> i) & 1u) {
      posmap[pos] = base + i;
      cmask[pos] = 1;
      ++pos;
    }
  }
}

// fp32 -> bf16 convert, 8 elems/thread
__global__ void cvt_f32_bf16(const float* __restrict__ X, bf16_t* __restrict__ Y, int n8) {
  int i = blockIdx.x * blockDim.x + threadIdx.x;
  if (i >= n8) return;
  float4 a = ((const float4*)X)[2 * i];
  float4 b = ((const float4*)X)[2 * i + 1];
  bf16x8 o;
  o[0] = (bf16_t)a.x; o[1] = (bf16_t)a.y; o[2] = (bf16_t)a.z; o[3] = (bf16_t)a.w;
  o[4] = (bf16_t)b.x; o[5] = (bf16_t)b.y; o[6] = (bf16_t)b.z; o[7] = (bf16_t)b.w;
  ((bf16x8*)Y)[i] = o;
}

// L2-normalize rows of length 1024, fp32 in -> bf16 out (for q)
__global__ void normalize_rows(const float* __restrict__ X, bf16_t* __restrict__ Y) {
  __shared__ float part[4];
  const int t = threadIdx.x;
  const size_t row = blockIdx.x;
  float4 v = ((const float4*)(X + row * 1024))[t];
  float s = v.x * v.x + v.y * v.y + v.z * v.z + v.w * v.w;
  #pragma unroll
  for (int m = 32; m >= 1; m >>= 1) s += __shfl_xor(s, m);
  if ((t & 63) == 0) part[t >> 6] = s;
  __syncthreads();
  float tot = part[0] + part[1] + part[2] + part[3];
  float r = rsqrtf(tot + 1e-6f);
  bf16x4 o;
  o[0] = (bf16_t)(v.x * r); o[1] = (bf16_t)(v.y * r);
  o[2] = (bf16_t)(v.z * r); o[3] = (bf16_t)(v.w * r);
  *(bf16x4*)&Y[row * 1024 + t * 4] = o;
}

// cmkn[p] = normalize(mk[posmap[p]]) for p<cnt; zeros for cnt<=p<mpad. No atomics.
__global__ void normalize_gather(const float* __restrict__ mk, const int* __restrict__ posmap,
                                 const int* __restrict__ smalls, bf16_t* __restrict__ cmkn) {
  __shared__ float part[4];
  const int p = blockIdx.x;
  const int cnt = smalls[0], mpad = smalls[1];
  if (p >= mpad) return;
  const int t = threadIdx.x;
  if (p >= cnt) {
    bf16x4 z;
    z[0] = z[1] = z[2] = z[3] = (bf16_t)0.f;
    *(bf16x4*)&cmkn[(size_t)p * 1024 + t * 4] = z;
    return;
  }
  const int slot = posmap[p];
  float4 v = ((const float4*)(mk + (size_t)slot * 1024))[t];
  float s = v.x * v.x + v.y * v.y + v.z * v.z + v.w * v.w;
  #pragma unroll
  for (int m = 32; m >= 1; m >>= 1) s += __shfl_xor(s, m);
  if ((t & 63) == 0) part[t >> 6] = s;
  __syncthreads();
  float tot = part[0] + part[1] + part[2] + part[3];
  float r = rsqrtf(tot + 1e-6f);
  bf16x4 o;
  o[0] = (bf16_t)(v.x * r); o[1] = (bf16_t)(v.y * r);
  o[2] = (bf16_t)(v.z * r); o[3] = (bf16_t)(v.w * r);
  *(bf16x4*)&cmkn[(size_t)p * 1024 + t * 4] = o;
}

// cVt[h][pos] = pos<cnt ? mv[posmap[pos]][h] : 0, for pos < mpad
__global__ void transpose_gather(const float* __restrict__ mv, const int* __restrict__ posmap,
                                 const int* __restrict__ smalls, bf16_t* __restrict__ cVt) {
  __shared__ float tile[32][33];
  const int cnt = smalls[0], mpad = smalls[1];
  const int p0 = blockIdx.y * 32;
  if (p0 >= mpad) return;
  const int tx = threadIdx.x & 31, ty = threadIdx.x >> 5;  // 32 x 8
  const int h0 = blockIdx.x * 32;
  #pragma unroll
  for (int j = 0; j < 32; j += 8) {
    const int pos = p0 + ty + j;
    float val = 0.f;
    if (pos < cnt) val = mv[(size_t)posmap[pos] * 1024 + h0 + tx];
    tile[ty + j][tx] = val;
  }
  __syncthreads();
  #pragma unroll
  for (int j = 0; j < 32; j += 8)
    cVt[(size_t)(h0 + ty + j) * MSLOTS + p0 + tx] = (bf16_t)tile[tx][ty + j];
}

__global__ void zero_f32(float* __restrict__ p, int n4) {
  int i = blockIdx.x * blockDim.x + threadIdx.x;
  if (i < n4) ((float4*)p)[i] = (float4){0.f, 0.f, 0.f, 0.f};
}

// out = retrf * (1/den[row]) -> bf16 (atomic split-K mode)
__global__ void scale_cvt(const float* __restrict__ retrf, const float* __restrict__ den,
                          bf16_t* __restrict__ out, int n4) {
  int i = blockIdx.x * blockDim.x + threadIdx.x;
  if (i >= n4) return;
  float4 s = ((const float4*)retrf)[i];
  const int row = (i * 4) >> 10;  // HDIM=1024
  const float r = 1.0f / den[row];
  bf16x4 o;
  o[0] = (bf16_t)(s.x * r); o[1] = (bf16_t)(s.y * r);
  o[2] = (bf16_t)(s.z * r); o[3] = (bf16_t)(s.w * r);
  ((bf16x4*)out)[i] = o;
}

// sum ks fp32 partial slabs, scale by 1/den[row], store bf16 (partial split-K mode)
__global__ void reduce_scale(const float* __restrict__ part, size_t partStride, int ks,
                             const float* __restrict__ den, bf16_t* __restrict__ out, int n4) {
  int i = blockIdx.x * blockDim.x + threadIdx.x;
  if (i >= n4) return;
  float4 s = ((const float4*)part)[i];
  for (int k = 1; k < ks; ++k) {
    float4 t = ((const float4*)(part + (size_t)k * partStride))[i];
    s.x += t.x; s.y += t.y; s.z += t.z; s.w += t.w;
  }
  const int row = (i * 4) >> 10;  // HDIM=1024
  const float r = 1.0f / den[row];
  bf16x4 o;
  o[0] = (bf16_t)(s.x * r); o[1] = (bf16_t)(s.y * r);
  o[2] = (bf16_t)(s.z * r); o[3] = (bf16_t)(s.w * r);
  ((bf16x4*)out)[i] = o;
}

// m97-style 128x128 bf16 GEMM, C = A * Bt^T. A:[rows,ldk], Bt:[N,ldk] row-major.
// All EPIs: XCD-aware block swizzle (y%8 fastest -> XCD under round-robin dispatch;
// then x, then y/8, then z). Verified r5->r6: G3 FETCH 581->146 MB.
// EPI 0: outf = acc + bias[col]                                   (fp32 out)
// EPI 1: outb = cmask[col] ? exp(10*acc) : 0 (bf16) + atomic row-sums into den
// EPI 3: split-K over K=mpad: atomicAdd(outf, acc)                (fp32 accumulate)
// EPI 4: split-K over K=mpad: outf[z-slab] = acc                  (fp32 partial store)
template <int EPI>
__global__ void gemm_bt(const bf16_t* __restrict__ A, const bf16_t* __restrict__ Bt,
                        int ldk, int kLenIn, int ldc,
                        const float* __restrict__ bias,
                        const int* __restrict__ cmask,
                        float* __restrict__ den,
                        float* __restrict__ outf, bf16_t* __restrict__ outb,
                        const int* __restrict__ smalls, int ks, size_t partStride) {
  __shared__ bf16_t lA[128 * 32];
  __shared__ bf16_t lB[128 * 32];
  const int t = threadIdx.x;
  const int lane = t & 63;
  const int wave = t >> 6;
  const int wm = (wave >> 1) << 6;  // wave tile origin (2x2 waves of 64x64)
  const int wn = (wave & 1) << 6;
  const int lr = lane & 15;
  const int lq = lane >> 4;

  int bx = blockIdx.x, by = blockIdx.y, bz = blockIdx.z;
  {
    const unsigned nx = gridDim.x, ny = gridDim.y;
    if ((ny & 7u) == 0u) {
      unsigned lin = blockIdx.x + nx * (blockIdx.y + ny * blockIdx.z);
      unsigned ylow = lin & 7u;
      lin >>= 3;
      bx = lin % nx;
      lin /= nx;
      unsigned yhigh = lin % (ny >> 3);
      bz = lin / (ny >> 3);
      by = ylow + 8u * yhigh;
    }
  }

  int kLen = kLenIn;
  int kstart = 0;
  if (EPI == 1) {
    if (bx * 128 >= smalls[1]) return;  // compacted N bound (block-uniform)
  }
  if (EPI == 3 || EPI == 4) {
    kLen = smalls[1] / ks;  // mpad % 512 == 0 -> kLen % 32 == 0 for ks in {4,8,16}
    kstart = bz * kLen;
  }

  // Tile staging: 128 rows x 32 K-cols = 8192 B per array; 256 thr x 16 B = half,
  // so each thread issues TWO global_load_lds per array (rows 0-63 and 64-127).
  const int r0 = t >> 2;         // 0..63
  const int c0 = (t & 3) * 8;    // 0,8,16,24
  const bf16_t* pA0 = A + (size_t)(by * 128 + r0) * ldk + kstart + c0;
  const bf16_t* pA1 = pA0 + (size_t)64 * ldk;
  const bf16_t* pB0 = Bt + (size_t)(bx * 128 + r0) * ldk + kstart + c0;
  const bf16_t* pB1 = pB0 + (size_t)64 * ldk;

  f32x4 acc[4][4];
  #pragma unroll
  for (int i = 0; i < 4; ++i)
    #pragma unroll
    for (int j = 0; j < 4; ++j) acc[i][j] = (f32x4){0.f, 0.f, 0.f, 0.f};

  for (int k0 = 0; k0 < kLen; k0 += 32) {
    __syncthreads();
    load16_lds(pA0, &lA[t * 8]);
    load16_lds(pA1, &lA[2048 + t * 8]);
    load16_lds(pB0, &lB[t * 8]);
    load16_lds(pB1, &lB[2048 + t * 8]);
    pA0 += 32; pA1 += 32; pB0 += 32; pB1 += 32;
    __syncthreads();
    bf16x8 af[4], bfr[4];
    #pragma unroll
    for (int i = 0; i < 4; ++i)
      af[i] = *(const bf16x8*)&lA[(wm + i * 16 + lr) * 32 + lq * 8];
    #pragma unroll
    for (int j = 0; j < 4; ++j)
      bfr[j] = *(const bf16x8*)&lB[(wn + j * 16 + lr) * 32 + lq * 8];
    #pragma unroll
    for (int i = 0; i < 4; ++i)
      #pragma unroll
      for (int j = 0; j < 4; ++j)
        acc[i][j] = __builtin_amdgcn_mfma_f32_16x16x32_bf16(af[i], bfr[j], acc[i][j], 0, 0, 0);
  }

  // C/D layout (m89-verified): col = lane&15, row = (lane>>4)*4 + r
  const int colBase = bx * 128 + wn + lr;
  const int rowBase = by * 128 + wm + lq * 4;

  if (EPI == 4) outf += (size_t)bz * partStride;

  float rs[4][4];  // per-(i,r) row-sum accumulators (EPI==1)
  if (EPI == 1) {
    #pragma unroll
    for (int i = 0; i < 4; ++i)
      #pragma unroll
      for (int r = 0; r < 4; ++r) rs[i][r] = 0.f;
  }

  #pragma unroll
  for (int j = 0; j < 4; ++j) {
    const int col = colBase + j * 16;
    float bval = 0.f;
    bool ok = true;
    if (EPI == 0) bval = bias[col];
    if (EPI == 1) ok = cmask[col] > 0;
    #pragma unroll
    for (int i = 0; i < 4; ++i) {
      const int row = rowBase + i * 16;
      #pragma unroll
      for (int r = 0; r < 4; ++r) {
        const size_t idx = (size_t)(row + r) * ldc + col;
        float v = acc[i][j][r];
        if (EPI == 0) outf[idx] = v + bval;
        if (EPI == 1) {
          float e = ok ? exp2f(v * 14.426950408889634f) : 0.f;
          rs[i][r] += e;
          outb[idx] = (bf16_t)e;
        }
        if (EPI == 3) atomicAdd(&outf[idx], v);
        if (EPI == 4) outf[idx] = v;
      }
    }
  }

  if (EPI == 1) {
    // reduce rs over the 16-lane col group (lr), then one atomic per row per wave
    #pragma unroll
    for (int i = 0; i < 4; ++i)
      #pragma unroll
      for (int r = 0; r < 4; ++r) {
        float s = rs[i][r];
        s += __shfl_xor(s, 1);
        s += __shfl_xor(s, 2);
        s += __shfl_xor(s, 4);
        s += __shfl_xor(s, 8);
        if (lr == 0) atomicAdd(&den[rowBase + i * 16 + r], s);
      }
  }
}

extern "C" void kernel_launch(void* const* d_in, const int* in_sizes, int n_in,
                              void* d_out, int out_size, void* d_ws, size_t ws_size,
                              hipStream_t stream) {
  const float* hs = (const float*)d_in[0];
  const float* Wk = (const float*)d_in[1];
  const float* bk = (const float*)d_in[2];
  // d_in[3]=Wv, d_in[4]=bv are unused by the reference
  const float* Wo = (const float*)d_in[5];
  const float* bo = (const float*)d_in[6];
  const float* mk = (const float*)d_in[7];
  const float* mv = (const float*)d_in[8];
  const int* usage = (const int*)d_in[9];
  float* out = (float*)d_out;

  char* ws = (char*)d_ws;
  size_t off = 0;
  auto alloc = [&](size_t b) -> void* {
    void* p = ws + off;
    off += (b + 255) & ~(size_t)255;
    return p;
  };
  // Persistent buffers (live across the chunk loop)
  bf16_t* cmkn = (bf16_t*)alloc((size_t)MSLOTS * HDIM * 2);
  bf16_t* cVt = (bf16_t*)alloc((size_t)HDIM * MSLOTS * 2);
  bf16_t* qnb = (bf16_t*)alloc((size_t)NROWS * HDIM * 2);
  bf16_t* retrb = (bf16_t*)alloc((size_t)NROWS * HDIM * 2);
  bf16_t* Wob = (bf16_t*)alloc((size_t)HDIM * HDIM * 2);
  float* den = (float*)alloc((size_t)NROWS * 4);
  int* posmap = (int*)alloc((size_t)MSLOTS * 4);
  int* cmask = (int*)alloc((size_t)MSLOTS * 4);
  int* smalls = (int*)alloc(256 * 4);
  const size_t fixed = off;

  // Overlay region: phase A = [hsb][Wkb][qf] (dead after stage 1);
  // loop = [P chunk][retrf or partial slabs]. Ladder: prefer partial-slab split-K
  // (no atomic RMW), fall back to atomic accumulate when ws is tight.
  int chunk = 128, ksplit = 4, partialMode = 0;
  {
    // (chunk, ks, partial?) in preference order
    const int cc[8] = {4096, 4096, 2048, 2048, 1024, 1024, 512, 128};
    const int kk[8] = {4, 4, 8, 8, 8, 8, 16, 4};
    const int pp[8] = {1, 0, 1, 0, 1, 0, 0, 0};
    for (int ci = 0; ci < 8; ++ci) {
      size_t outBytes = pp[ci] ? (size_t)cc[ci] * HDIM * 4 * kk[ci] : (size_t)cc[ci] * HDIM * 4;
      size_t region = (size_t)cc[ci] * MSLOTS * 2 + outBytes;
      size_t phaseA = (size_t)NROWS * HDIM * 2 + (size_t)HDIM * HDIM * 2 +
                      (size_t)NROWS * HDIM * 4 + 1024;
      if (region < phaseA) region = phaseA;
      if (fixed + region <= ws_size) {
        chunk = cc[ci]; ksplit = kk[ci]; partialMode = pp[ci];
        break;
      }
    }
  }
  bf16_t* hsb = (bf16_t*)(ws + fixed);
  bf16_t* Wkb = (bf16_t*)(ws + fixed + (size_t)NROWS * HDIM * 2);
  float* qf = (float*)(ws + fixed + (size_t)NROWS * HDIM * 2 + (size_t)HDIM * HDIM * 2);
  bf16_t* P = (bf16_t*)(ws + fixed);
  float* retrf = (float*)(ws + fixed + (size_t)chunk * MSLOTS * 2);  // or slab base
  const size_t partStride = (size_t)chunk * HDIM;

  // ---- stage 0: compaction + dtype prep ----
  init_compact<<<MSLOTS / 256, 256, 0, stream>>>(cmask);
  compact_scan<<<1, 1024, 0, stream>>>(usage, posmap, cmask, smalls);
  cvt_f32_bf16<<<(NROWS * HDIM / 8 + 255) / 256, 256, 0, stream>>>(hs, hsb, NROWS * HDIM / 8);
  cvt_f32_bf16<<<(HDIM * HDIM / 8 + 255) / 256, 256, 0, stream>>>(Wk, Wkb, HDIM * HDIM / 8);
  cvt_f32_bf16<<<(HDIM * HDIM / 8 + 255) / 256, 256, 0, stream>>>(Wo, Wob, HDIM * HDIM / 8);
  normalize_gather<<<MSLOTS, 256, 0, stream>>>(mk, posmap, smalls, cmkn);
  transpose_gather<<<dim3(HDIM / 32, MSLOTS / 32), 256, 0, stream>>>(mv, posmap, smalls, cVt);

  // ---- stage 1: q = hs @ Wk^T + bk (fp32), then normalize -> qn bf16 ----
  gemm_bt<0><<<dim3(HDIM / 128, NROWS / 128), 256, 0, stream>>>(
      hsb, Wkb, HDIM, HDIM, HDIM, bk, nullptr, nullptr, qf, nullptr, smalls, 1, 0);
  normalize_rows<<<NROWS, 256, 0, stream>>>(qf, qnb);

  // ---- stage 2/3: P = exp(10 * qn@cmkn^T) masked (+row sums); retr = P@V / den ----
  for (int c = 0; c < NROWS; c += chunk) {
    zero_f32<<<(chunk / 4 + 255) / 256, 256, 0, stream>>>(den, chunk / 4);
    gemm_bt<1><<<dim3(MSLOTS / 128, chunk / 128), 256, 0, stream>>>(
        qnb + (size_t)c * HDIM, cmkn, HDIM, HDIM, MSLOTS, nullptr, cmask, den, nullptr, P,
        smalls, 1, 0);
    if (partialMode) {
      gemm_bt<4><<<dim3(HDIM / 128, chunk / 128, ksplit), 256, 0, stream>>>(
          P, cVt, MSLOTS, 0, HDIM, nullptr, nullptr, nullptr, retrf, nullptr, smalls, ksplit,
          partStride);
      reduce_scale<<<(chunk * HDIM / 4 + 255) / 256, 256, 0, stream>>>(
          retrf, partStride, ksplit, den, retrb + (size_t)c * HDIM, chunk * HDIM / 4);
    } else {
      zero_f32<<<(chunk * HDIM / 4 + 255) / 256, 256, 0, stream>>>(retrf, chunk * HDIM / 4);
      gemm_bt<3><<<dim3(HDIM / 128, chunk / 128, ksplit), 256, 0, stream>>>(
          P, cVt, MSLOTS, 0, HDIM, nullptr, nullptr, nullptr, retrf, nullptr, smalls, ksplit,
          0);
      scale_cvt<<<(chunk * HDIM / 4 + 255) / 256, 256, 0, stream>>>(
          retrf, den, retrb + (size_t)c * HDIM, chunk * HDIM / 4);
    }
  }

  // ---- stage 4: out = retrieved @ Wo^T + bo (fp32) ----
  gemm_bt<0><<<dim3(HDIM / 128, NROWS / 128), 256, 0, stream>>>(
      retrb, Wob, HDIM, HDIM, HDIM, bo, nullptr, nullptr, out, nullptr, smalls, 1, 0);
}

// Round 8
// 837.689 us; speedup vs baseline: 1.7921x; 1.0655x over previous
//
#include <hip/hip_runtime.h>
#include <hip/hip_bf16.h>
#include <stdint.h>
#include <stddef.h>

typedef __bf16 bf16_t;
typedef __attribute__((ext_vector_type(8))) __bf16 bf16x8;
typedef __attribute__((ext_vector_type(4))) __bf16 bf16x4;
typedef __attribute__((ext_vector_type(4))) float f32x4;

#define HDIM 1024
#define MSLOTS 16384
#define NROWS 8192  // B*S

__device__ __forceinline__ void load16_lds(const void* g, void* l) {
  __builtin_amdgcn_global_load_lds((const __attribute__((address_space(1))) void*)g,
                                   (__attribute__((address_space(3))) void*)l, 16, 0, 0);
}

// zero the compacted mask
__global__ void init_compact(int* __restrict__ cmask) {
  int i = blockIdx.x * blockDim.x + threadIdx.x;
  if (i < MSLOTS) cmask[i] = 0;
}

// Single-block deterministic compaction: posmap[pos] = slot for used slots (sorted),
// cmask[pos] = 1, smalls[0] = count, smalls[1] = count padded to mult of 512.
__global__ void compact_scan(const int* __restrict__ usage, int* __restrict__ posmap,
                             int* __restrict__ cmask, int* __restrict__ smalls) {
  __shared__ int wtot[16], wbase[16];
  const int t = threadIdx.x;          // 0..1023
  const int lane = t & 63, wid = t >> 6;
  const int base = t * 16;
  unsigned mask = 0;
  int c = 0;
  #pragma unroll
  for (int i = 0; i < 16; ++i) {
    if (usage[base + i] > 0) { mask |= (1u << i); ++c; }
  }
  int inc = c;
  #pragma unroll
  for (int d = 1; d < 64; d <<= 1) {
    int n = __shfl_up(inc, d);
    if (lane >= d) inc += n;
  }
  if (lane == 63) wtot[wid] = inc;
  __syncthreads();
  if (t == 0) {
    int acc = 0;
    #pragma unroll
    for (int w = 0; w < 16; ++w) { wbase[w] = acc; acc += wtot[w]; }
    smalls[0] = acc;
    smalls[1] = ((acc + 511) >> 9) << 9;
  }
  __syncthreads();
  int pos = wbase[wid] + inc - c;
  #pragma unroll
  for (int i = 0; i < 16; ++i) {
    if ((mask >> i) & 1u) {
      posmap[pos] = base + i;
      cmask[pos] = 1;
      ++pos;
    }
  }
}

// fp32 -> bf16 convert, 8 elems/thread
__global__ void cvt_f32_bf16(const float* __restrict__ X, bf16_t* __restrict__ Y, int n8) {
  int i = blockIdx.x * blockDim.x + threadIdx.x;
  if (i >= n8) return;
  float4 a = ((const float4*)X)[2 * i];
  float4 b = ((const float4*)X)[2 * i + 1];
  bf16x8 o;
  o[0] = (bf16_t)a.x; o[1] = (bf16_t)a.y; o[2] = (bf16_t)a.z; o[3] = (bf16_t)a.w;
  o[4] = (bf16_t)b.x; o[5] = (bf16_t)b.y; o[6] = (bf16_t)b.z; o[7] = (bf16_t)b.w;
  ((bf16x8*)Y)[i] = o;
}

// L2-normalize rows of length 1024, fp32 in -> bf16 out (for q)
__global__ void normalize_rows(const float* __restrict__ X, bf16_t* __restrict__ Y) {
  __shared__ float part[4];
  const int t = threadIdx.x;
  const size_t row = blockIdx.x;
  float4 v = ((const float4*)(X + row * 1024))[t];
  float s = v.x * v.x + v.y * v.y + v.z * v.z + v.w * v.w;
  #pragma unroll
  for (int m = 32; m >= 1; m >>= 1) s += __shfl_xor(s, m);
  if ((t & 63) == 0) part[t >> 6] = s;
  __syncthreads();
  float tot = part[0] + part[1] + part[2] + part[3];
  float r = rsqrtf(tot + 1e-6f);
  bf16x4 o;
  o[0] = (bf16_t)(v.x * r); o[1] = (bf16_t)(v.y * r);
  o[2] = (bf16_t)(v.z * r); o[3] = (bf16_t)(v.w * r);
  *(bf16x4*)&Y[row * 1024 + t * 4] = o;
}

// cmkn[p] = normalize(mk[posmap[p]]) for p<cnt; zeros for cnt<=p<mpad. No atomics.
__global__ void normalize_gather(const float* __restrict__ mk, const int* __restrict__ posmap,
                                 const int* __restrict__ smalls, bf16_t* __restrict__ cmkn) {
  __shared__ float part[4];
  const int p = blockIdx.x;
  const int cnt = smalls[0], mpad = smalls[1];
  if (p >= mpad) return;
  const int t = threadIdx.x;
  if (p >= cnt) {
    bf16x4 z;
    z[0] = z[1] = z[2] = z[3] = (bf16_t)0.f;
    *(bf16x4*)&cmkn[(size_t)p * 1024 + t * 4] = z;
    return;
  }
  const int slot = posmap[p];
  float4 v = ((const float4*)(mk + (size_t)slot * 1024))[t];
  float s = v.x * v.x + v.y * v.y + v.z * v.z + v.w * v.w;
  #pragma unroll
  for (int m = 32; m >= 1; m >>= 1) s += __shfl_xor(s, m);
  if ((t & 63) == 0) part[t >> 6] = s;
  __syncthreads();
  float tot = part[0] + part[1] + part[2] + part[3];
  float r = rsqrtf(tot + 1e-6f);
  bf16x4 o;
  o[0] = (bf16_t)(v.x * r); o[1] = (bf16_t)(v.y * r);
  o[2] = (bf16_t)(v.z * r); o[3] = (bf16_t)(v.w * r);
  *(bf16x4*)&cmkn[(size_t)p * 1024 + t * 4] = o;
}

// cVt[h][pos] = pos<cnt ? mv[posmap[pos]][h] : 0, for pos < mpad
__global__ void transpose_gather(const float* __restrict__ mv, const int* __restrict__ posmap,
                                 const int* __restrict__ smalls, bf16_t* __restrict__ cVt) {
  __shared__ float tile[32][33];
  const int cnt = smalls[0], mpad = smalls[1];
  const int p0 = blockIdx.y * 32;
  if (p0 >= mpad) return;
  const int tx = threadIdx.x & 31, ty = threadIdx.x >> 5;  // 32 x 8
  const int h0 = blockIdx.x * 32;
  #pragma unroll
  for (int j = 0; j < 32; j += 8) {
    const int pos = p0 + ty + j;
    float val = 0.f;
    if (pos < cnt) val = mv[(size_t)posmap[pos] * 1024 + h0 + tx];
    tile[ty + j][tx] = val;
  }
  __syncthreads();
  #pragma unroll
  for (int j = 0; j < 32; j += 8)
    cVt[(size_t)(h0 + ty + j) * MSLOTS + p0 + tx] = (bf16_t)tile[tx][ty + j];
}

__global__ void zero_f32(float* __restrict__ p, int n4) {
  int i = blockIdx.x * blockDim.x + threadIdx.x;
  if (i < n4) ((float4*)p)[i] = (float4){0.f, 0.f, 0.f, 0.f};
}

// out = retrf * (1/den[row]) -> bf16 (atomic split-K mode)
__global__ void scale_cvt(const float* __restrict__ retrf, const float* __restrict__ den,
                          bf16_t* __restrict__ out, int n4) {
  int i = blockIdx.x * blockDim.x + threadIdx.x;
  if (i >= n4) return;
  float4 s = ((const float4*)retrf)[i];
  const int row = (i * 4) >> 10;  // HDIM=1024
  const float r = 1.0f / den[row];
  bf16x4 o;
  o[0] = (bf16_t)(s.x * r); o[1] = (bf16_t)(s.y * r);
  o[2] = (bf16_t)(s.z * r); o[3] = (bf16_t)(s.w * r);
  ((bf16x4*)out)[i] = o;
}

// sum ks fp32 partial slabs, scale by 1/den[row], store bf16 (partial split-K mode)
__global__ void reduce_scale(const float* __restrict__ part, size_t partStride, int ks,
                             const float* __restrict__ den, bf16_t* __restrict__ out, int n4) {
  int i = blockIdx.x * blockDim.x + threadIdx.x;
  if (i >= n4) return;
  float4 s = ((const float4*)part)[i];
  for (int k = 1; k < ks; ++k) {
    float4 t = ((const float4*)(part + (size_t)k * partStride))[i];
    s.x += t.x; s.y += t.y; s.z += t.z; s.w += t.w;
  }
  const int row = (i * 4) >> 10;  // HDIM=1024
  const float r = 1.0f / den[row];
  bf16x4 o;
  o[0] = (bf16_t)(s.x * r); o[1] = (bf16_t)(s.y * r);
  o[2] = (bf16_t)(s.z * r); o[3] = (bf16_t)(s.w * r);
  ((bf16x4*)out)[i] = o;
}

// m97-style 128x128 bf16 GEMM, C = A * Bt^T. A:[rows,ldk], Bt:[N,ldk] row-major.
// All EPIs: XCD swizzle, y-INNER order: ylow (3b -> XCD via round-robin), then
// yhigh, then x, then z. The 4 y-siblings of an x-block are stream-adjacent on
// one XCD -> shared B-tile is L2-hot when reused (reuse distance ~4 blocks),
// A-tiles recur every 4th block. (r6's x-inner order left B reuse distance =
// 23 MB -> L2 miss every stage; FETCH was 337 MB on G2.)
// EPI 0: outf = acc + bias[col]                                   (fp32 out)
// EPI 1: outb = cmask[col] ? exp(10*acc) : 0 (bf16) + atomic row-sums into den
// EPI 3: split-K over K=mpad: atomicAdd(outf, acc)                (fp32 accumulate)
// EPI 4: split-K over K=mpad: outf[z-slab] = acc                  (fp32 partial store)
template <int EPI>
__global__ void gemm_bt(const bf16_t* __restrict__ A, const bf16_t* __restrict__ Bt,
                        int ldk, int kLenIn, int ldc,
                        const float* __restrict__ bias,
                        const int* __restrict__ cmask,
                        float* __restrict__ den,
                        float* __restrict__ outf, bf16_t* __restrict__ outb,
                        const int* __restrict__ smalls, int ks, size_t partStride) {
  __shared__ bf16_t lA[128 * 32];
  __shared__ bf16_t lB[128 * 32];
  const int t = threadIdx.x;
  const int lane = t & 63;
  const int wave = t >> 6;
  const int wm = (wave >> 1) << 6;  // wave tile origin (2x2 waves of 64x64)
  const int wn = (wave & 1) << 6;
  const int lr = lane & 15;
  const int lq = lane >> 4;

  int bx = blockIdx.x, by = blockIdx.y, bz = blockIdx.z;
  {
    const unsigned nx = gridDim.x, ny = gridDim.y;
    if ((ny & 7u) == 0u) {
      unsigned lin = blockIdx.x + nx * (blockIdx.y + ny * blockIdx.z);
      unsigned ylow = lin & 7u;   // XCD id under round-robin dispatch
      lin >>= 3;
      const unsigned nyh = ny >> 3;
      unsigned yhigh = lin % nyh; // y-inner: B-tile reused by stream-adjacent blocks
      lin /= nyh;
      bx = lin % nx;
      bz = lin / nx;
      by = ylow + 8u * yhigh;
    }
  }

  int kLen = kLenIn;
  int kstart = 0;
  if (EPI == 1) {
    if (bx * 128 >= smalls[1]) return;  // compacted N bound (block-uniform)
  }
  if (EPI == 3 || EPI == 4) {
    kLen = smalls[1] / ks;  // mpad % 512 == 0 -> kLen % 32 == 0 for ks in {4,8,16}
    kstart = bz * kLen;
  }

  // Tile staging: 128 rows x 32 K-cols = 8192 B per array; 256 thr x 16 B = half,
  // so each thread issues TWO global_load_lds per array (rows 0-63 and 64-127).
  const int r0 = t >> 2;         // 0..63
  const int c0 = (t & 3) * 8;    // 0,8,16,24
  const bf16_t* pA0 = A + (size_t)(by * 128 + r0) * ldk + kstart + c0;
  const bf16_t* pA1 = pA0 + (size_t)64 * ldk;
  const bf16_t* pB0 = Bt + (size_t)(bx * 128 + r0) * ldk + kstart + c0;
  const bf16_t* pB1 = pB0 + (size_t)64 * ldk;

  f32x4 acc[4][4];
  #pragma unroll
  for (int i = 0; i < 4; ++i)
    #pragma unroll
    for (int j = 0; j < 4; ++j) acc[i][j] = (f32x4){0.f, 0.f, 0.f, 0.f};

  for (int k0 = 0; k0 < kLen; k0 += 32) {
    __syncthreads();
    load16_lds(pA0, &lA[t * 8]);
    load16_lds(pA1, &lA[2048 + t * 8]);
    load16_lds(pB0, &lB[t * 8]);
    load16_lds(pB1, &lB[2048 + t * 8]);
    pA0 += 32; pA1 += 32; pB0 += 32; pB1 += 32;
    __syncthreads();
    bf16x8 af[4], bfr[4];
    #pragma unroll
    for (int i = 0; i < 4; ++i)
      af[i] = *(const bf16x8*)&lA[(wm + i * 16 + lr) * 32 + lq * 8];
    #pragma unroll
    for (int j = 0; j < 4; ++j)
      bfr[j] = *(const bf16x8*)&lB[(wn + j * 16 + lr) * 32 + lq * 8];
    #pragma unroll
    for (int i = 0; i < 4; ++i)
      #pragma unroll
      for (int j = 0; j < 4; ++j)
        acc[i][j] = __builtin_amdgcn_mfma_f32_16x16x32_bf16(af[i], bfr[j], acc[i][j], 0, 0, 0);
  }

  // C/D layout (m89-verified): col = lane&15, row = (lane>>4)*4 + r
  const int colBase = bx * 128 + wn + lr;
  const int rowBase = by * 128 + wm + lq * 4;

  if (EPI == 4) outf += (size_t)bz * partStride;

  float rs[4][4];  // per-(i,r) row-sum accumulators (EPI==1)
  if (EPI == 1) {
    #pragma unroll
    for (int i = 0; i < 4; ++i)
      #pragma unroll
      for (int r = 0; r < 4; ++r) rs[i][r] = 0.f;
  }

  #pragma unroll
  for (int j = 0; j < 4; ++j) {
    const int col = colBase + j * 16;
    float bval = 0.f;
    bool ok = true;
    if (EPI == 0) bval = bias[col];
    if (EPI == 1) ok = cmask[col] > 0;
    #pragma unroll
    for (int i = 0; i < 4; ++i) {
      const int row = rowBase + i * 16;
      #pragma unroll
      for (int r = 0; r < 4; ++r) {
        const size_t idx = (size_t)(row + r) * ldc + col;
        float v = acc[i][j][r];
        if (EPI == 0) outf[idx] = v + bval;
        if (EPI == 1) {
          float e = ok ? exp2f(v * 14.426950408889634f) : 0.f;
          rs[i][r] += e;
          outb[idx] = (bf16_t)e;
        }
        if (EPI == 3) atomicAdd(&outf[idx], v);
        if (EPI == 4) outf[idx] = v;
      }
    }
  }

  if (EPI == 1) {
    // reduce rs over the 16-lane col group (lr), then one atomic per row per wave
    #pragma unroll
    for (int i = 0; i < 4; ++i)
      #pragma unroll
      for (int r = 0; r < 4; ++r) {
        float s = rs[i][r];
        s += __shfl_xor(s, 1);
        s += __shfl_xor(s, 2);
        s += __shfl_xor(s, 4);
        s += __shfl_xor(s, 8);
        if (lr == 0) atomicAdd(&den[rowBase + i * 16 + r], s);
      }
  }
}

extern "C" void kernel_launch(void* const* d_in, const int* in_sizes, int n_in,
                              void* d_out, int out_size, void* d_ws, size_t ws_size,
                              hipStream_t stream) {
  const float* hs = (const float*)d_in[0];
  const float* Wk = (const float*)d_in[1];
  const float* bk = (const float*)d_in[2];
  // d_in[3]=Wv, d_in[4]=bv are unused by the reference
  const float* Wo = (const float*)d_in[5];
  const float* bo = (const float*)d_in[6];
  const float* mk = (const float*)d_in[7];
  const float* mv = (const float*)d_in[8];
  const int* usage = (const int*)d_in[9];
  float* out = (float*)d_out;

  char* ws = (char*)d_ws;
  size_t off = 0;
  auto alloc = [&](size_t b) -> void* {
    void* p = ws + off;
    off += (b + 255) & ~(size_t)255;
    return p;
  };
  // Persistent buffers (live across the chunk loop)
  bf16_t* cmkn = (bf16_t*)alloc((size_t)MSLOTS * HDIM * 2);
  bf16_t* cVt = (bf16_t*)alloc((size_t)HDIM * MSLOTS * 2);
  bf16_t* qnb = (bf16_t*)alloc((size_t)NROWS * HDIM * 2);
  bf16_t* retrb = (bf16_t*)alloc((size_t)NROWS * HDIM * 2);
  bf16_t* Wob = (bf16_t*)alloc((size_t)HDIM * HDIM * 2);
  float* den = (float*)alloc((size_t)NROWS * 4);
  int* posmap = (int*)alloc((size_t)MSLOTS * 4);
  int* cmask = (int*)alloc((size_t)MSLOTS * 4);
  int* smalls = (int*)alloc(256 * 4);
  const size_t fixed = off;

  // Overlay region: phase A = [hsb][Wkb][qf] (dead after stage 1);
  // loop = [P chunk][retrf or partial slabs]. Ladder: prefer partial-slab split-K
  // (no atomic RMW), fall back to atomic accumulate when ws is tight.
  int chunk = 128, ksplit = 4, partialMode = 0;
  {
    // (chunk, ks, partial?) in preference order
    const int cc[8] = {4096, 4096, 2048, 2048, 1024, 1024, 512, 128};
    const int kk[8] = {4, 4, 8, 8, 8, 8, 16, 4};
    const int pp[8] = {1, 0, 1, 0, 1, 0, 0, 0};
    for (int ci = 0; ci < 8; ++ci) {
      size_t outBytes = pp[ci] ? (size_t)cc[ci] * HDIM * 4 * kk[ci] : (size_t)cc[ci] * HDIM * 4;
      size_t region = (size_t)cc[ci] * MSLOTS * 2 + outBytes;
      size_t phaseA = (size_t)NROWS * HDIM * 2 + (size_t)HDIM * HDIM * 2 +
                      (size_t)NROWS * HDIM * 4 + 1024;
      if (region < phaseA) region = phaseA;
      if (fixed + region <= ws_size) {
        chunk = cc[ci]; ksplit = kk[ci]; partialMode = pp[ci];
        break;
      }
    }
  }
  bf16_t* hsb = (bf16_t*)(ws + fixed);
  bf16_t* Wkb = (bf16_t*)(ws + fixed + (size_t)NROWS * HDIM * 2);
  float* qf = (float*)(ws + fixed + (size_t)NROWS * HDIM * 2 + (size_t)HDIM * HDIM * 2);
  bf16_t* P = (bf16_t*)(ws + fixed);
  float* retrf = (float*)(ws + fixed + (size_t)chunk * MSLOTS * 2);  // or slab base
  const size_t partStride = (size_t)chunk * HDIM;

  // ---- stage 0: compaction + dtype prep ----
  init_compact<<<MSLOTS / 256, 256, 0, stream>>>(cmask);
  compact_scan<<<1, 1024, 0, stream>>>(usage, posmap, cmask, smalls);
  cvt_f32_bf16<<<(NROWS * HDIM / 8 + 255) / 256, 256, 0, stream>>>(hs, hsb, NROWS * HDIM / 8);
  cvt_f32_bf16<<<(HDIM * HDIM / 8 + 255) / 256, 256, 0, stream>>>(Wk, Wkb, HDIM * HDIM / 8);
  cvt_f32_bf16<<<(HDIM * HDIM / 8 + 255) / 256, 256, 0, stream>>>(Wo, Wob, HDIM * HDIM / 8);
  normalize_gather<<<MSLOTS, 256, 0, stream>>>(mk, posmap, smalls, cmkn);
  transpose_gather<<<dim3(HDIM / 32, MSLOTS / 32), 256, 0, stream>>>(mv, posmap, smalls, cVt);

  // ---- stage 1: q = hs @ Wk^T + bk (fp32), then normalize -> qn bf16 ----
  gemm_bt<0><<<dim3(HDIM / 128, NROWS / 128), 256, 0, stream>>>(
      hsb, Wkb, HDIM, HDIM, HDIM, bk, nullptr, nullptr, qf, nullptr, smalls, 1, 0);
  normalize_rows<<<NROWS, 256, 0, stream>>>(qf, qnb);

  // ---- stage 2/3: P = exp(10 * qn@cmkn^T) masked (+row sums); retr = P@V / den ----
  for (int c = 0; c < NROWS; c += chunk) {
    zero_f32<<<(chunk / 4 + 255) / 256, 256, 0, stream>>>(den, chunk / 4);
    gemm_bt<1><<<dim3(MSLOTS / 128, chunk / 128), 256, 0, stream>>>(
        qnb + (size_t)c * HDIM, cmkn, HDIM, HDIM, MSLOTS, nullptr, cmask, den, nullptr, P,
        smalls, 1, 0);
    if (partialMode) {
      gemm_bt<4><<<dim3(HDIM / 128, chunk / 128, ksplit), 256, 0, stream>>>(
          P, cVt, MSLOTS, 0, HDIM, nullptr, nullptr, nullptr, retrf, nullptr, smalls, ksplit,
          partStride);
      reduce_scale<<<(chunk * HDIM / 4 + 255) / 256, 256, 0, stream>>>(
          retrf, partStride, ksplit, den, retrb + (size_t)c * HDIM, chunk * HDIM / 4);
    } else {
      zero_f32<<<(chunk * HDIM / 4 + 255) / 256, 256, 0, stream>>>(retrf, chunk * HDIM / 4);
      gemm_bt<3><<<dim3(HDIM / 128, chunk / 128, ksplit), 256, 0, stream>>>(
          P, cVt, MSLOTS, 0, HDIM, nullptr, nullptr, nullptr, retrf, nullptr, smalls, ksplit,
          0);
      scale_cvt<<<(chunk * HDIM / 4 + 255) / 256, 256, 0, stream>>>(
          retrf, den, retrb + (size_t)c * HDIM, chunk * HDIM / 4);
    }
  }

  // ---- stage 4: out = retrieved @ Wo^T + bo (fp32) ----
  gemm_bt<0><<<dim3(HDIM / 128, NROWS / 128), 256, 0, stream>>>(
      retrb, Wob, HDIM, HDIM, HDIM, bo, nullptr, nullptr, out, nullptr, smalls, 1, 0);
}